// Round 7
// baseline (367.861 us; speedup 1.0000x reference)
//
#include <hip/hip_runtime.h>
#include <math.h>

// ---------------------------------------------------------------------------
// Problem: B=4, L=4096, D=P=256, tau=0.5
// out = (1/8) * sum_{b,l} [ log(S1-e^2) + log(S2-e^2) - 4*d[b,l] ]
//   S[b,q] = sum_{m<2L} exp(2 * Zhat[b,q].Zhat[b,m]),  Zhat = [z1n; z2n]
// R18: 512-THREAD BLOCKS for gram + fusedproj -> 16 waves/CU (4/SIMD),
// double R17's 8.  Theory: every kernel was latency-bound at 2 waves/SIMD
// (grid 512 x 256thr = 2 blocks/CU; MfmaUtil 17-20% everywhere).
//  - gram: R16's proven dbuf-LDS structure, 8 waves = 4wm(32-row) x
//    2wn(64-col).  VGPR audit: afr[2][2]=32 + acc[2][4]=32 + rs 8 +
//    transients ~116 < 128 -> __launch_bounds__(512,4) pins 4 waves/SIMD
//    without spill.  Col-sum planes now 4/row-stripe (256/batch).
//  - fusedproj: 8 waves x 32 cols each (acc[4][2], ~90 VGPR), same LDS.
//  - final_log: np = (q>>7)*4 planes.
// ---------------------------------------------------------------------------

typedef __attribute__((ext_vector_type(8))) short short8;
typedef __attribute__((ext_vector_type(4))) short short4v;
typedef __attribute__((ext_vector_type(4))) float float4v;
typedef __attribute__((ext_vector_type(8))) int int8v;
typedef __attribute__((ext_vector_type(4))) int int4v;

#if defined(__has_builtin)
#if __has_builtin(__builtin_amdgcn_exp2f)
#define EXP2F(x) __builtin_amdgcn_exp2f(x)
#endif
#endif
#ifndef EXP2F
#define EXP2F(x) __expf(0.69314718056f * (x))
#endif

__device__ __forceinline__ short f2bf(float f) {
    unsigned u = __builtin_bit_cast(unsigned, f);
    u += 0x7fffu + ((u >> 16) & 1u);          // RNE
    return (short)(u >> 16);
}

// manual fp32 -> fp8 e4m3fn (OCP), RNE.  |f| <= ~1.7 here.
__device__ __forceinline__ unsigned char f2fp8(float f) {
    float af = fabsf(f);
    unsigned s = (__builtin_bit_cast(unsigned, f) >> 31) << 7;
    if (af < 0.015625f) {                     // subnormal (<2^-6); 8 rolls up
        int q = (int)rintf(af * 512.0f);
        return (unsigned char)(s | (unsigned)q);
    }
    unsigned au = __builtin_bit_cast(unsigned, af);
    au += 0x7FFFFu + ((au >> 20) & 1u);       // RNE at bit 20
    int e = (int)(au >> 23) - 127;
    unsigned m = (au >> 20) & 7u;
    return (unsigned char)(s | (unsigned)((e + 7) << 3) | m);
}

__device__ __forceinline__ void gl_lds16(const void* g, void* l) {
    __builtin_amdgcn_global_load_lds(
        (const __attribute__((address_space(1))) void*)g,
        (__attribute__((address_space(3))) void*)l, 16, 0, 0);
}

// ---------------------------------------------------------------------------
// convW + zero: W1/W2 fp32 -> bf16 and zero S + out.  grid 128 x 256.
// ---------------------------------------------------------------------------
__global__ __launch_bounds__(256) void convW_zero_kernel(
    const float* __restrict__ W1, const float* __restrict__ W2,
    short* __restrict__ d1, short* __restrict__ d2,
    float* __restrict__ S, float* __restrict__ out)
{
    int i = blockIdx.x * 256 + threadIdx.x;   // 0..32767
    const float* src = (i < 16384) ? W1 : W2;
    short* dst = (i < 16384) ? d1 : d2;
    int j = i & 16383;
    float4v v = ((const float4v*)src)[j];
    short4v o;
    o.x = f2bf(v.x); o.y = f2bf(v.y); o.z = f2bf(v.z); o.w = f2bf(v.w);
    ((short4v*)dst)[j] = o;
    S[i] = 0.f;
    if (i == 0) *out = 0.f;
}

// ---------------------------------------------------------------------------
// fused proj, 512 threads (8 waves, each 64 rows x 32 cols):
//   phase1: acc = X*W1^T  (X fp32 -> bf16 in-register; W1 staged in lsB)
//           -> +b1, elu -> bf16 -> lsH [p>>3][row][p&7]
//   phase2: acc = H*W2^T (A from lsH, W2 staged per kt)
//   epilogue: +b2, rownorm -> zn8 = fp8(sqrt(2*log2e)*z/||z||)
// grid 512 x 512thr.  LDS ~67KB -> 2 blocks/CU = 16 waves/CU.
// ---------------------------------------------------------------------------
__global__ __launch_bounds__(512, 4) void fusedproj_kernel(
    const float* __restrict__ X1, const float* __restrict__ X2,
    const short* __restrict__ W1bf, const float* __restrict__ b1,
    const short* __restrict__ W2bf, const float* __restrict__ b2,
    unsigned char* __restrict__ zn8)
{
    __shared__ short lsB[16384];   // 32KB W1/W2 staging [kc][256 rows][8]
    __shared__ short lsH[16384];   // 32KB H, staged layout
    __shared__ float rssq[8][64];
    __shared__ float rinv[64];

    const int arow0 = blockIdx.x * 64;
    const int tid  = threadIdx.x;
    const int w    = tid >> 6;     // 0..7: 32-col slice
    const int lane = tid & 63;
    const int quad = lane >> 4;
    const int l15  = lane & 15;

    const int set = arow0 >> 14;
    const float* Xs = (set ? X2 : X1) + (size_t)(arow0 & 16383) * 256;

    float4v acc[4][2];
#pragma unroll
    for (int mi = 0; mi < 4; ++mi)
#pragma unroll
        for (int ni = 0; ni < 2; ++ni)
            acc[mi][ni] = (float4v){0.f, 0.f, 0.f, 0.f};

    // ---- phase 1: X * W1^T  (X fp32 -> bf16 in-register)
    for (int kt = 0; kt < 4; ++kt) {
        const int kbase = kt * 64;
#pragma unroll
        for (int r = 0; r < 4; ++r) {
            const int c   = w * 4 + r;        // 32 chunks of W1
            const int s   = c * 64 + lane;
            const int kc  = s >> 8;
            const int row = s & 255;
            gl_lds16(W1bf + (size_t)row * 256 + kbase + kc * 8,
                     lsB + (size_t)c * 512);
        }
        __syncthreads();
#pragma unroll
        for (int ks = 0; ks < 2; ++ks) {
            const int kc = ks * 4 + quad;
            short8 af[4], bfv[2];
#pragma unroll
            for (int mi = 0; mi < 4; ++mi) {
                const float* xp = Xs + (size_t)(mi * 16 + l15) * 256
                                  + kbase + kc * 8;
                float4v a0 = *(const float4v*)xp;
                float4v a1 = *(const float4v*)(xp + 4);
                short8 t;
                t[0] = f2bf(a0.x); t[1] = f2bf(a0.y);
                t[2] = f2bf(a0.z); t[3] = f2bf(a0.w);
                t[4] = f2bf(a1.x); t[5] = f2bf(a1.y);
                t[6] = f2bf(a1.z); t[7] = f2bf(a1.w);
                af[mi] = t;
            }
#pragma unroll
            for (int ni = 0; ni < 2; ++ni)
                bfv[ni] = *(const short8*)(lsB +
                    ((size_t)kc * 256 + w * 32 + ni * 16 + l15) * 8);
#pragma unroll
            for (int mi = 0; mi < 4; ++mi)
#pragma unroll
                for (int ni = 0; ni < 2; ++ni)
                    acc[mi][ni] = __builtin_amdgcn_mfma_f32_16x16x32_bf16(
                        af[mi], bfv[ni], acc[mi][ni], 0, 0, 0);
        }
        __syncthreads();
    }

    // ---- epilogue 1: +b1, elu, bf16 -> lsH  (local rows 0..63)
    {
#pragma unroll
        for (int ni = 0; ni < 2; ++ni) {
            const int pcol = w * 32 + ni * 16 + l15;
            const float bv = b1[pcol];
#pragma unroll
            for (int mi = 0; mi < 4; ++mi)
#pragma unroll
                for (int reg = 0; reg < 4; ++reg) {
                    const int row = mi * 16 + quad * 4 + reg;
                    float v = acc[mi][ni][reg] + bv;
                    v = (v > 0.f) ? v : expm1f(v);
                    lsH[(size_t)(pcol >> 3) * 512 + row * 8 + (pcol & 7)] = f2bf(v);
                }
        }
    }

    // ---- phase 2: H * W2^T  (A from lsH, B = W2 staged per kt)
#pragma unroll
    for (int mi = 0; mi < 4; ++mi)
#pragma unroll
        for (int ni = 0; ni < 2; ++ni)
            acc[mi][ni] = (float4v){0.f, 0.f, 0.f, 0.f};

    for (int kt = 0; kt < 4; ++kt) {
        const int kbase = kt * 64;
#pragma unroll
        for (int r = 0; r < 4; ++r) {
            const int c   = w * 4 + r;
            const int s   = c * 64 + lane;
            const int kc  = s >> 8;
            const int row = s & 255;
            gl_lds16(W2bf + (size_t)row * 256 + kbase + kc * 8,
                     lsB + (size_t)c * 512);
        }
        __syncthreads();                      // kt=0: also guards lsH writes
#pragma unroll
        for (int ks = 0; ks < 2; ++ks) {
            const int kc = ks * 4 + quad;
            short8 af[4], bfv[2];
#pragma unroll
            for (int mi = 0; mi < 4; ++mi)
                af[mi] = *(const short8*)(lsH +
                    ((size_t)(kt * 8 + kc) * 64 + mi * 16 + l15) * 8);
#pragma unroll
            for (int ni = 0; ni < 2; ++ni)
                bfv[ni] = *(const short8*)(lsB +
                    ((size_t)kc * 256 + w * 32 + ni * 16 + l15) * 8);
#pragma unroll
            for (int mi = 0; mi < 4; ++mi)
#pragma unroll
                for (int ni = 0; ni < 2; ++ni)
                    acc[mi][ni] = __builtin_amdgcn_mfma_f32_16x16x32_bf16(
                        af[mi], bfv[ni], acc[mi][ni], 0, 0, 0);
        }
        __syncthreads();
    }

    // ---- epilogue 2: +b2, normalize, fp8 out (sqrt(2*log2e) folded)
#pragma unroll
    for (int ni = 0; ni < 2; ++ni) {
        const float bv = b2[w * 32 + ni * 16 + l15];
#pragma unroll
        for (int mi = 0; mi < 4; ++mi)
#pragma unroll
            for (int reg = 0; reg < 4; ++reg)
                acc[mi][ni][reg] += bv;
    }
    float ps[4][4];
#pragma unroll
    for (int mi = 0; mi < 4; ++mi)
#pragma unroll
        for (int reg = 0; reg < 4; ++reg) {
            float s = 0.f;
#pragma unroll
            for (int ni = 0; ni < 2; ++ni) {
                float v = acc[mi][ni][reg];
                s += v * v;
            }
            s += __shfl_xor(s, 1); s += __shfl_xor(s, 2);
            s += __shfl_xor(s, 4); s += __shfl_xor(s, 8);
            ps[mi][reg] = s;
        }
    if (l15 == 0) {
#pragma unroll
        for (int mi = 0; mi < 4; ++mi)
#pragma unroll
            for (int reg = 0; reg < 4; ++reg)
                rssq[w][mi * 16 + quad * 4 + reg] = ps[mi][reg];
    }
    __syncthreads();
    if (tid < 64) {
        float ssq = 0.f;
#pragma unroll
        for (int j = 0; j < 8; ++j) ssq += rssq[j][tid];
        rinv[tid] = 1.69864360f / fmaxf(sqrtf(ssq), 1e-12f);
    }
    __syncthreads();

    const int r0  = arow0;                 // multiple of 64
    const int bb  = (r0 >> 12) & 3;
    const int l0  = r0 & 4095;
    unsigned char* dst = zn8 + ((size_t)(bb * 2 + set) * 4096 + l0) * 256;
#pragma unroll
    for (int mi = 0; mi < 4; ++mi)
#pragma unroll
        for (int reg = 0; reg < 4; ++reg) {
            const int rl = mi * 16 + quad * 4 + reg;
            const float inv = rinv[rl];
#pragma unroll
            for (int ni = 0; ni < 2; ++ni)
                dst[(size_t)rl * 256 + w * 32 + ni * 16 + l15] =
                    f2fp8(acc[mi][ni][reg] * inv);
        }
}

// ---------------------------------------------------------------------------
// FP8 symmetric flash-gram R18: grid 512 x 512thr (8 waves: 4wm x 2wn,
// wave = 32 rows x 64 cols).  Block = (batch, pair p, quarter); pair =
// row-stripes {p, 63-p}, 65 tiles, quarters 17/16/16/16.  Dbuf 2x32KB
// B staging (gl_lds16); A-frags (fp8, 32 VGPR) persistent per row-stripe.
// Row-sums in regs -> atomic flush per stripe.  Col-sums (symmetry) per
// off-diag tile -> non-atomic store into plane Cc[batch][4*row+wm][8192].
// Cross tiles (tj==row+32): d-dot extraction before exp.
// 16 waves/CU (2 blocks x 8 waves); VGPR ~116 <= 128 via (512,4).
// ---------------------------------------------------------------------------
#if defined(__has_builtin)
#if __has_builtin(__builtin_amdgcn_mfma_scale_f32_16x16x128_f8f6f4)
#define HAVE_MX 1
#endif
#endif

__global__ __launch_bounds__(512, 4) void gram_fp8_sym_kernel(
    const unsigned char* __restrict__ zn8, float* __restrict__ S,
    float* __restrict__ Cc, float* __restrict__ out)
{
    __shared__ unsigned char lsB[2][32768];   // [buf][kp 0..15][col 0..127][16B]

    const int bx    = blockIdx.x;             // 0..511
    const int xcd   = bx & 7;                 // batch -> XCD pair {2b,2b+1}
    const int batch = xcd >> 1;
    const int sub   = (bx >> 3) * 2 + (xcd & 1);   // 0..127
    const int p     = sub >> 2;               // pair 0..31
    const int qu    = sub & 3;                // quarter
    const int u0    = (qu == 0) ? 0 : 17 + (qu - 1) * 16;
    const int u1    = u0 + ((qu == 0) ? 17 : 16);
    const int ubrk  = 64 - p;                 // first tile index of row 63-p

    const unsigned char* Z = zn8 + (size_t)batch * 2097152;

    const int tid  = threadIdx.x;
    const int w    = tid >> 6;                // 0..7
    const int lane = tid & 63;
    const int wm   = w & 3;                   // 32-row quarter
    const int wn   = w >> 2;                  // 64-col half
    const int quad = lane >> 4;
    const int l15  = lane & 15;

#define TJ_OF(u)  ((u) < ubrk ? p + (u) : (u) - 1)
#define ROW_OF(u) ((u) < ubrk ? p : 63 - p)

#define STAGE_B(t, buf)                                                       \
    {                                                                         \
        const unsigned char* Bb = Z + (size_t)(t) * 128 * 256;                \
        _Pragma("unroll")                                                     \
        for (int r = 0; r < 4; ++r) {                                         \
            const int c   = w * 4 + r;                                        \
            const int u_  = c * 64 + lane;                                    \
            const int kp  = u_ >> 7;                                          \
            const int col = u_ & 127;                                         \
            gl_lds16(Bb + (size_t)col * 256 + kp * 16,                        \
                     &lsB[buf][(size_t)c * 1024]);                            \
        }                                                                     \
    }

    float rs[2][4];
#pragma unroll
    for (int mi = 0; mi < 2; ++mi)
#pragma unroll
        for (int reg = 0; reg < 4; ++reg)
            rs[mi][reg] = 0.f;
    float dsum = 0.f;

#define FLUSH_RS(rowstripe)                                                   \
    {                                                                         \
        float* Sr = S + (size_t)batch * 8192 + (rowstripe) * 128 + wm * 32;   \
        _Pragma("unroll")                                                     \
        for (int mi = 0; mi < 2; ++mi)                                        \
            _Pragma("unroll")                                                 \
            for (int reg = 0; reg < 4; ++reg) {                               \
                float v = rs[mi][reg];                                        \
                v += __shfl_xor(v, 1); v += __shfl_xor(v, 2);                 \
                v += __shfl_xor(v, 4); v += __shfl_xor(v, 8);                 \
                if (l15 == 0)                                                 \
                    atomicAdd(&Sr[mi * 16 + quad * 4 + reg], v);              \
                rs[mi][reg] = 0.f;                                            \
            }                                                                 \
    }

    int currow = ROW_OF(u0);

#ifdef HAVE_MX
    int8v afr[2][2];
#define LOAD_A(rowstripe)                                                     \
    {                                                                         \
        const unsigned char* Ab = Z + (size_t)((rowstripe) * 128 + wm * 32) * 256; \
        _Pragma("unroll")                                                     \
        for (int mi = 0; mi < 2; ++mi)                                        \
            _Pragma("unroll")                                                 \
            for (int ks = 0; ks < 2; ++ks) {                                  \
                const unsigned char* pA = Ab + (size_t)(mi * 16 + l15) * 256  \
                                          + ks * 128 + quad * 32;             \
                int4v lo = *(const int4v*)pA;                                 \
                int4v hi = *(const int4v*)(pA + 16);                          \
                afr[mi][ks] = __builtin_shufflevector(lo, hi, 0,1,2,3,4,5,6,7); \
            }                                                                 \
    }
#else
    long afr[2][8];
#define LOAD_A(rowstripe)                                                     \
    {                                                                         \
        const unsigned char* Ab = Z + (size_t)((rowstripe) * 128 + wm * 32) * 256; \
        _Pragma("unroll")                                                     \
        for (int mi = 0; mi < 2; ++mi)                                        \
            _Pragma("unroll")                                                 \
            for (int kc = 0; kc < 8; ++kc)                                    \
                afr[mi][kc] = *(const long*)(Ab + (size_t)(mi * 16 + l15) * 256 \
                                             + kc * 32 + quad * 8);           \
    }
#endif

    LOAD_A(currow);
    STAGE_B(TJ_OF(u0), 0);
    __syncthreads();

    for (int ui = u0; ui < u1; ++ui) {
        const int buf = (ui - u0) & 1;
        const int row = ROW_OF(ui);
        const int tj  = TJ_OF(ui);
        if (row != currow) {                  // crossed into row 63-p
            FLUSH_RS(currow);
            LOAD_A(row);
            currow = row;
        }
        if (ui + 1 < u1) STAGE_B(TJ_OF(ui + 1), buf ^ 1);

        float4v acc[2][4];
#pragma unroll
        for (int mi = 0; mi < 2; ++mi)
#pragma unroll
            for (int ni = 0; ni < 4; ++ni)
                acc[mi][ni] = (float4v){0.f, 0.f, 0.f, 0.f};

        const unsigned char* lb = &lsB[buf][0];
        __builtin_amdgcn_s_setprio(1);
#ifdef HAVE_MX
#pragma unroll
        for (int ks = 0; ks < 2; ++ks) {
            const int kp0 = ks * 8 + quad * 2;
            int8v bfv[4];
#pragma unroll
            for (int ni = 0; ni < 4; ++ni) {
                const unsigned char* pB = lb +
                    ((size_t)kp0 * 128 + wn * 64 + ni * 16 + l15) * 16;
                int4v lo = *(const int4v*)pB;
                int4v hi = *(const int4v*)(pB + 2048);   // kp0+1 slot
                bfv[ni] = __builtin_shufflevector(lo, hi, 0,1,2,3,4,5,6,7);
            }
#pragma unroll
            for (int mi = 0; mi < 2; ++mi)
#pragma unroll
                for (int ni = 0; ni < 4; ++ni)
                    acc[mi][ni] = __builtin_amdgcn_mfma_scale_f32_16x16x128_f8f6f4(
                        afr[mi][ks], bfv[ni], acc[mi][ni],
                        0, 0,                     // cbsz=E4M3, blgp=E4M3
                        0, 0x7F7F7F7F,            // scale A = 1.0
                        0, 0x7F7F7F7F);           // scale B = 1.0
        }
#else
#pragma unroll
        for (int kc = 0; kc < 8; ++kc) {
            const int kseg = kc * 4 + quad;
            const int kp   = kseg >> 1;
            const int hf   = kseg & 1;
            long bfv[4];
#pragma unroll
            for (int ni = 0; ni < 4; ++ni)
                bfv[ni] = *(const long*)(lb +
                    ((size_t)kp * 128 + wn * 64 + ni * 16 + l15) * 16 + hf * 8);
#pragma unroll
            for (int mi = 0; mi < 2; ++mi)
#pragma unroll
                for (int ni = 0; ni < 4; ++ni)
                    acc[mi][ni] = __builtin_amdgcn_mfma_f32_16x16x32_fp8_fp8(
                        afr[mi][kc], bfv[ni], acc[mi][ni], 0, 0, 0);
        }
#endif
        __builtin_amdgcn_s_setprio(0);

        // ---- cross tile: extract (q,q+4096) dots (raw acc, BEFORE exp)
        if (tj == row + 32) {
#pragma unroll
            for (int mi = 0; mi < 2; ++mi)
#pragma unroll
                for (int ni = 0; ni < 4; ++ni)
#pragma unroll
                    for (int reg = 0; reg < 4; ++reg) {
                        const int r = wm * 32 + mi * 16 + quad * 4 + reg;
                        const int c = wn * 64 + ni * 16 + l15;
                        if (r == c) dsum += acc[mi][ni][reg];
                    }
        }

        // ---- exp2 in place (acc already = 2*log2e*dot via zn8 scaling)
#pragma unroll
        for (int mi = 0; mi < 2; ++mi)
#pragma unroll
            for (int ni = 0; ni < 4; ++ni)
#pragma unroll
                for (int reg = 0; reg < 4; ++reg)
                    acc[mi][ni][reg] = EXP2F(acc[mi][ni][reg]);

        // ---- row sums accumulate in regs
#pragma unroll
        for (int mi = 0; mi < 2; ++mi)
#pragma unroll
            for (int reg = 0; reg < 4; ++reg)
                rs[mi][reg] += acc[mi][0][reg] + acc[mi][1][reg]
                             + acc[mi][2][reg] + acc[mi][3][reg];

        // ---- col sums (symmetry): per-wave 32-row partial -> own plane
        if (tj > row) {
            float* Cd = Cc + ((size_t)batch * 256 + row * 4 + wm) * 8192
                        + tj * 128 + wn * 64;
#pragma unroll
            for (int ni = 0; ni < 4; ++ni) {
                float s = 0.f;
#pragma unroll
                for (int mi = 0; mi < 2; ++mi)
#pragma unroll
                    for (int reg = 0; reg < 4; ++reg)
                        s += acc[mi][ni][reg];
                s += __shfl_xor(s, 16); s += __shfl_xor(s, 32);
                if (quad == 0)
                    Cd[ni * 16 + l15] = s;
            }
        }
        __syncthreads();                      // single per-tile barrier
    }

    FLUSH_RS(currow);

    // dv = 2*log2e * sum(d);  need -0.5*sum(d) -> factor -0.25*ln2
    {
        float dv = dsum;
        dv += __shfl_xor(dv, 1);  dv += __shfl_xor(dv, 2);
        dv += __shfl_xor(dv, 4);  dv += __shfl_xor(dv, 8);
        dv += __shfl_xor(dv, 16); dv += __shfl_xor(dv, 32);
        if (lane == 0 && dv != 0.f)
            atomicAdd(out, -0.17328680f * dv);
    }
#undef STAGE_B
#undef LOAD_A
#undef FLUSH_RS
#undef TJ_OF
#undef ROW_OF
}

// ---------------------------------------------------------------------------
// final: out += 0.125 * sum_{b,q} log(S[b][q] + sum_{r<4*(q>>7)} Cc[b][r][q] - e^2)
// grid 128 x 256 (one thread per (b,q)).  Only valid (written) planes read.
// ---------------------------------------------------------------------------
__global__ __launch_bounds__(256) void final_log_kernel(
    const float* __restrict__ S, const float* __restrict__ Cc,
    float* __restrict__ out)
{
    __shared__ float red[4];
    const int tid  = threadIdx.x;
    const int w    = tid >> 6;
    const int lane = tid & 63;
    const float E2 = 7.3890560989306495f;

    const int i = blockIdx.x * 256 + tid;     // 0..32767
    const int b = i >> 13;
    const int q = i & 8191;
    float s = S[i];
    const float* Cp = Cc + (size_t)b * 256 * 8192 + q;
    const int np = (q >> 7) * 4;              // planes 0..np-1 are written
    for (int r = 0; r < np; ++r)
        s += Cp[(size_t)r * 8192];
    float acc = logf(s - E2);

    acc += __shfl_xor(acc, 1);  acc += __shfl_xor(acc, 2);
    acc += __shfl_xor(acc, 4);  acc += __shfl_xor(acc, 8);
    acc += __shfl_xor(acc, 16); acc += __shfl_xor(acc, 32);
    if (lane == 0) red[w] = acc;
    __syncthreads();
    if (tid == 0)
        atomicAdd(out, 0.125f * (red[0] + red[1] + red[2] + red[3]));
}

// ---------------------------------------------------------------------------
// Workspace (bytes), total ~42.3 MB:
//   [0,       131072)  S (4*8192 fp32)
//   [131072,  262144)  W1bf
//   [262144,  393216)  W2bf
//   [393216,  8781824) zn8 (fp8, 8.39MB)
//   [8781824, 42336256) Cc (col-sum planes, 4*256*8192 fp32 = 33.55MB;
//                      no memset: final reads only written planes)
// ---------------------------------------------------------------------------
extern "C" void kernel_launch(void* const* d_in, const int* in_sizes, int n_in,
                              void* d_out, int out_size, void* d_ws, size_t ws_size,
                              hipStream_t stream)
{
    const float* X1 = (const float*)d_in[0];
    const float* X2 = (const float*)d_in[1];
    const float* W1 = (const float*)d_in[2];
    const float* b1 = (const float*)d_in[3];
    const float* W2 = (const float*)d_in[4];
    const float* b2 = (const float*)d_in[5];

    char* ws = (char*)d_ws;
    float* S    = (float*)(ws + 0);
    short* W1bf = (short*)(ws + 131072);
    short* W2bf = (short*)(ws + 262144);
    unsigned char* zn8 = (unsigned char*)(ws + 393216);
    float* Cc   = (float*)(ws + 8781824);

    convW_zero_kernel<<<128, 256, 0, stream>>>(W1, W2, W1bf, W2bf,
                                               S, (float*)d_out);
    fusedproj_kernel<<<512, 512, 0, stream>>>(X1, X2, W1bf, b1, W2bf, b2, zn8);
    gram_fp8_sym_kernel<<<512, 512, 0, stream>>>(zn8, S, Cc, (float*)d_out);
    final_log_kernel<<<128, 256, 0, stream>>>(S, Cc, (float*)d_out);
}

// Round 8
// 239.828 us; speedup vs baseline: 1.5339x; 1.5339x over previous
//
#include <hip/hip_runtime.h>
#include <math.h>

// ---------------------------------------------------------------------------
// Problem: B=4, L=4096, D=P=256, tau=0.5
// out = (1/8) * sum_{b,l} [ log(S1-e^2) + log(S2-e^2) - 4*d[b,l] ]
//   S[b,q] = sum_{m<2L} exp(2 * Zhat[b,q].Zhat[b,m]),  Zhat = [z1n; z2n]
// R19: occupancy via GRID SIZE, not thread count (R18 lesson: forcing
// VGPR<=128 spills catastrophically; R17 lesson: 512-block grids cap at
// 8 waves/CU).  Both hot kernels -> 1024 blocks x 256 thr, (256,3) bounds
// (cap 170 regs >= ~140 need, spill-free), small LDS -> 4 blocks/CU =
// 16 waves/CU (4/SIMD).
//  - gram: pairs (p,63-p) split into EIGHTHS (9/8*7 tiles); 4 waves = 4 wm
//    32-row bands; B staged per 64-col chunk, dbuf 2x16KB = 32KB LDS.
//    Col-sum planes Cc[batch][4*row+wm] (as R18).  acc[2][4], afr[2][2].
//  - fusedproj: 1024 blocks x 32 rows.  X loaded ONCE cooperatively ->
//    bf16 lsX (16KB) — R17/R18 had 4x duplicate X HBM reads (~256MB).
//    W1/W2 frags direct from global (L2-hot, no staging barriers).
//    lsH 16KB.  LDS ~33KB.
// ---------------------------------------------------------------------------

typedef __attribute__((ext_vector_type(8))) short short8;
typedef __attribute__((ext_vector_type(4))) short short4v;
typedef __attribute__((ext_vector_type(4))) float float4v;
typedef __attribute__((ext_vector_type(8))) int int8v;
typedef __attribute__((ext_vector_type(4))) int int4v;

#if defined(__has_builtin)
#if __has_builtin(__builtin_amdgcn_exp2f)
#define EXP2F(x) __builtin_amdgcn_exp2f(x)
#endif
#endif
#ifndef EXP2F
#define EXP2F(x) __expf(0.69314718056f * (x))
#endif

__device__ __forceinline__ short f2bf(float f) {
    unsigned u = __builtin_bit_cast(unsigned, f);
    u += 0x7fffu + ((u >> 16) & 1u);          // RNE
    return (short)(u >> 16);
}

// manual fp32 -> fp8 e4m3fn (OCP), RNE.  |f| <= ~1.7 here.
__device__ __forceinline__ unsigned char f2fp8(float f) {
    float af = fabsf(f);
    unsigned s = (__builtin_bit_cast(unsigned, f) >> 31) << 7;
    if (af < 0.015625f) {                     // subnormal (<2^-6); 8 rolls up
        int q = (int)rintf(af * 512.0f);
        return (unsigned char)(s | (unsigned)q);
    }
    unsigned au = __builtin_bit_cast(unsigned, af);
    au += 0x7FFFFu + ((au >> 20) & 1u);       // RNE at bit 20
    int e = (int)(au >> 23) - 127;
    unsigned m = (au >> 20) & 7u;
    return (unsigned char)(s | (unsigned)((e + 7) << 3) | m);
}

__device__ __forceinline__ void gl_lds16(const void* g, void* l) {
    __builtin_amdgcn_global_load_lds(
        (const __attribute__((address_space(1))) void*)g,
        (__attribute__((address_space(3))) void*)l, 16, 0, 0);
}

// ---------------------------------------------------------------------------
// convW + zero: W1/W2 fp32 -> bf16 and zero S + out.  grid 128 x 256.
// ---------------------------------------------------------------------------
__global__ __launch_bounds__(256) void convW_zero_kernel(
    const float* __restrict__ W1, const float* __restrict__ W2,
    short* __restrict__ d1, short* __restrict__ d2,
    float* __restrict__ S, float* __restrict__ out)
{
    int i = blockIdx.x * 256 + threadIdx.x;   // 0..32767
    const float* src = (i < 16384) ? W1 : W2;
    short* dst = (i < 16384) ? d1 : d2;
    int j = i & 16383;
    float4v v = ((const float4v*)src)[j];
    short4v o;
    o.x = f2bf(v.x); o.y = f2bf(v.y); o.z = f2bf(v.z); o.w = f2bf(v.w);
    ((short4v*)dst)[j] = o;
    S[i] = 0.f;
    if (i == 0) *out = 0.f;
}

// ---------------------------------------------------------------------------
// fused proj R19: 1024 blocks x 256 thr, 32-row tiles, 4 waves x 64 cols.
//   stage: X tile (32x256 fp32) -> coop load+convert -> lsX bf16 staged
//   phase1: acc[2][4] = X*W1^T  (A from lsX, W1 frags DIRECT from global)
//           -> +b1, elu -> bf16 -> lsH
//   phase2: acc[2][4] = H*W2^T  (A from lsH, W2 frags direct from global)
//   epilogue: +b2, rownorm -> zn8 = fp8(sqrt(2*log2e)*z/||z||)
// LDS 33KB -> 4 blocks/CU = 16 waves/CU.
// ---------------------------------------------------------------------------
__global__ __launch_bounds__(256, 3) void fusedproj_kernel(
    const float* __restrict__ X1, const float* __restrict__ X2,
    const short* __restrict__ W1bf, const float* __restrict__ b1,
    const short* __restrict__ W2bf, const float* __restrict__ b2,
    unsigned char* __restrict__ zn8)
{
    __shared__ short lsX[8192];    // 16KB: [kc 0..31][row 0..31][8]
    __shared__ short lsH[8192];    // 16KB: [pc 0..31][row 0..31][8]
    __shared__ float rssq[4][32];
    __shared__ float rinv[32];

    const int arow0 = blockIdx.x * 32;
    const int tid  = threadIdx.x;
    const int w    = tid >> 6;     // 0..3: 64-col slice
    const int lane = tid & 63;
    const int quad = lane >> 4;
    const int l15  = lane & 15;

    const int set = arow0 >> 14;
    const float* Xs = (set ? X2 : X1) + (size_t)(arow0 & 16383) * 256;

    // ---- stage X: 32 rows x 256 fp32, coop load + f2bf -> lsX
#pragma unroll
    for (int i = 0; i < 4; ++i) {
        const int oct = i * 256 + tid;        // 0..1023 octets (row, k-octet)
        const int row = oct >> 5;
        const int kc  = oct & 31;
        const float* xp = Xs + (size_t)row * 256 + kc * 8;
        float4v a0 = *(const float4v*)xp;
        float4v a1 = *(const float4v*)(xp + 4);
        short8 t;
        t[0] = f2bf(a0.x); t[1] = f2bf(a0.y);
        t[2] = f2bf(a0.z); t[3] = f2bf(a0.w);
        t[4] = f2bf(a1.x); t[5] = f2bf(a1.y);
        t[6] = f2bf(a1.z); t[7] = f2bf(a1.w);
        *(short8*)(lsX + (size_t)kc * 256 + row * 8) = t;
    }
    __syncthreads();

    float4v acc[2][4];
#pragma unroll
    for (int mi = 0; mi < 2; ++mi)
#pragma unroll
        for (int ni = 0; ni < 4; ++ni)
            acc[mi][ni] = (float4v){0.f, 0.f, 0.f, 0.f};

    // ---- phase 1: X * W1^T  (W1 frags from global, L2-hot)
#pragma unroll
    for (int kt = 0; kt < 4; ++kt)
#pragma unroll
        for (int ks = 0; ks < 2; ++ks) {
            const int kcg = kt * 8 + ks * 4 + quad;   // 0..31
            short8 af[2], bfv[4];
#pragma unroll
            for (int mi = 0; mi < 2; ++mi)
                af[mi] = *(const short8*)(lsX +
                    (size_t)kcg * 256 + (mi * 16 + l15) * 8);
#pragma unroll
            for (int ni = 0; ni < 4; ++ni)
                bfv[ni] = *(const short8*)(W1bf +
                    (size_t)(w * 64 + ni * 16 + l15) * 256 + kcg * 8);
#pragma unroll
            for (int mi = 0; mi < 2; ++mi)
#pragma unroll
                for (int ni = 0; ni < 4; ++ni)
                    acc[mi][ni] = __builtin_amdgcn_mfma_f32_16x16x32_bf16(
                        af[mi], bfv[ni], acc[mi][ni], 0, 0, 0);
        }

    // ---- epilogue 1: +b1, elu, bf16 -> lsH  (local rows 0..31)
#pragma unroll
    for (int ni = 0; ni < 4; ++ni) {
        const int pcol = w * 64 + ni * 16 + l15;
        const float bv = b1[pcol];
#pragma unroll
        for (int mi = 0; mi < 2; ++mi)
#pragma unroll
            for (int reg = 0; reg < 4; ++reg) {
                const int row = mi * 16 + quad * 4 + reg;
                float v = acc[mi][ni][reg] + bv;
                v = (v > 0.f) ? v : expm1f(v);
                lsH[(size_t)(pcol >> 3) * 256 + row * 8 + (pcol & 7)] = f2bf(v);
            }
    }
    __syncthreads();

    // ---- phase 2: H * W2^T  (A from lsH, W2 frags from global)
#pragma unroll
    for (int mi = 0; mi < 2; ++mi)
#pragma unroll
        for (int ni = 0; ni < 4; ++ni)
            acc[mi][ni] = (float4v){0.f, 0.f, 0.f, 0.f};

#pragma unroll
    for (int kt = 0; kt < 4; ++kt)
#pragma unroll
        for (int ks = 0; ks < 2; ++ks) {
            const int kcg = kt * 8 + ks * 4 + quad;
            short8 af[2], bfv[4];
#pragma unroll
            for (int mi = 0; mi < 2; ++mi)
                af[mi] = *(const short8*)(lsH +
                    (size_t)kcg * 256 + (mi * 16 + l15) * 8);
#pragma unroll
            for (int ni = 0; ni < 4; ++ni)
                bfv[ni] = *(const short8*)(W2bf +
                    (size_t)(w * 64 + ni * 16 + l15) * 256 + kcg * 8);
#pragma unroll
            for (int mi = 0; mi < 2; ++mi)
#pragma unroll
                for (int ni = 0; ni < 4; ++ni)
                    acc[mi][ni] = __builtin_amdgcn_mfma_f32_16x16x32_bf16(
                        af[mi], bfv[ni], acc[mi][ni], 0, 0, 0);
        }

    // ---- epilogue 2: +b2, normalize, fp8 out (sqrt(2*log2e) folded)
#pragma unroll
    for (int ni = 0; ni < 4; ++ni) {
        const float bv = b2[w * 64 + ni * 16 + l15];
#pragma unroll
        for (int mi = 0; mi < 2; ++mi)
#pragma unroll
            for (int reg = 0; reg < 4; ++reg)
                acc[mi][ni][reg] += bv;
    }
    float ps[2][4];
#pragma unroll
    for (int mi = 0; mi < 2; ++mi)
#pragma unroll
        for (int reg = 0; reg < 4; ++reg) {
            float s = 0.f;
#pragma unroll
            for (int ni = 0; ni < 4; ++ni) {
                float v = acc[mi][ni][reg];
                s += v * v;
            }
            s += __shfl_xor(s, 1); s += __shfl_xor(s, 2);
            s += __shfl_xor(s, 4); s += __shfl_xor(s, 8);
            ps[mi][reg] = s;
        }
    if (l15 == 0) {
#pragma unroll
        for (int mi = 0; mi < 2; ++mi)
#pragma unroll
            for (int reg = 0; reg < 4; ++reg)
                rssq[w][mi * 16 + quad * 4 + reg] = ps[mi][reg];
    }
    __syncthreads();
    if (tid < 32) {
        float ssq = rssq[0][tid] + rssq[1][tid] + rssq[2][tid] + rssq[3][tid];
        rinv[tid] = 1.69864360f / fmaxf(sqrtf(ssq), 1e-12f);
    }
    __syncthreads();

    const int bb  = (arow0 >> 12) & 3;
    const int l0  = arow0 & 4095;
    unsigned char* dst = zn8 + ((size_t)(bb * 2 + set) * 4096 + l0) * 256;
#pragma unroll
    for (int mi = 0; mi < 2; ++mi)
#pragma unroll
        for (int reg = 0; reg < 4; ++reg) {
            const int rl = mi * 16 + quad * 4 + reg;
            const float inv = rinv[rl];
#pragma unroll
            for (int ni = 0; ni < 4; ++ni)
                dst[(size_t)rl * 256 + w * 64 + ni * 16 + l15] =
                    f2fp8(acc[mi][ni][reg] * inv);
        }
}

// ---------------------------------------------------------------------------
// FP8 symmetric flash-gram R19: grid 1024 x 256thr (4 waves = 4 wm 32-row
// bands, all waves share cols).  Block = (batch, pair p, eighth e); pair =
// row-stripes {p, 63-p}, 65 tiles (9/8/8/8/8/8/8/8).  B staged per 64-COL
// CHUNK: dbuf 2x16KB = 32KB LDS -> 4 blocks/CU.  A-frags (fp8, 32 VGPR)
// persistent per row-stripe.  Row-sums in regs -> atomic flush per stripe.
// Col-sums per off-diag chunk -> non-atomic into Cc[batch][4*row+wm].
// Cross tiles (tj==row+32): d-dot extraction before exp.
// ---------------------------------------------------------------------------
#if defined(__has_builtin)
#if __has_builtin(__builtin_amdgcn_mfma_scale_f32_16x16x128_f8f6f4)
#define HAVE_MX 1
#endif
#endif

__global__ __launch_bounds__(256, 3) void gram_fp8_sym_kernel(
    const unsigned char* __restrict__ zn8, float* __restrict__ S,
    float* __restrict__ Cc, float* __restrict__ out)
{
    __shared__ unsigned char lsB[2][16384];   // [buf][kp 0..15][col 0..63][16B]

    const int bx    = blockIdx.x;             // 0..1023
    const int xcd   = bx & 7;                 // batch -> XCD pair {2b,2b+1}
    const int batch = xcd >> 1;
    const int sub   = (bx >> 3) * 2 + (xcd & 1);   // 0..255
    const int p     = sub >> 3;               // pair 0..31
    const int e     = sub & 7;                // eighth
    const int u0    = (e == 0) ? 0 : 9 + (e - 1) * 8;
    const int u1    = u0 + ((e == 0) ? 9 : 8);
    const int ubrk  = 64 - p;                 // first tile index of row 63-p

    const unsigned char* Z = zn8 + (size_t)batch * 2097152;

    const int tid  = threadIdx.x;
    const int w    = tid >> 6;                // 0..3
    const int lane = tid & 63;
    const int wm   = w;                       // 32-row band
    const int quad = lane >> 4;
    const int l15  = lane & 15;

#define TJ_OF(u)  ((u) < ubrk ? p + (u) : (u) - 1)
#define ROW_OF(u) ((u) < ubrk ? p : 63 - p)

// chunk = 64 cols x 256B = 16KB; [kp 0..15][col 0..63][16B]
#define STAGE_CHUNK(t, half, buf)                                             \
    {                                                                         \
        const unsigned char* Bb = Z + ((size_t)(t) * 128 + (half) * 64) * 256;\
        _Pragma("unroll")                                                     \
        for (int r = 0; r < 4; ++r) {                                         \
            const int c   = w * 4 + r;        /* 16 chunks of 1KB */          \
            const int u_  = c * 64 + lane;                                    \
            const int kp  = u_ >> 6;                                          \
            const int col = u_ & 63;                                          \
            gl_lds16(Bb + (size_t)col * 256 + kp * 16,                        \
                     &lsB[buf][(size_t)c * 1024]);                            \
        }                                                                     \
    }

    float rs[2][4];
#pragma unroll
    for (int mi = 0; mi < 2; ++mi)
#pragma unroll
        for (int reg = 0; reg < 4; ++reg)
            rs[mi][reg] = 0.f;
    float dsum = 0.f;

#define FLUSH_RS(rowstripe)                                                   \
    {                                                                         \
        float* Sr = S + (size_t)batch * 8192 + (rowstripe) * 128 + wm * 32;   \
        _Pragma("unroll")                                                     \
        for (int mi = 0; mi < 2; ++mi)                                        \
            _Pragma("unroll")                                                 \
            for (int reg = 0; reg < 4; ++reg) {                               \
                float v = rs[mi][reg];                                        \
                v += __shfl_xor(v, 1); v += __shfl_xor(v, 2);                 \
                v += __shfl_xor(v, 4); v += __shfl_xor(v, 8);                 \
                if (l15 == 0)                                                 \
                    atomicAdd(&Sr[mi * 16 + quad * 4 + reg], v);              \
                rs[mi][reg] = 0.f;                                            \
            }                                                                 \
    }

    int currow = ROW_OF(u0);

#ifdef HAVE_MX
    int8v afr[2][2];
#define LOAD_A(rowstripe)                                                     \
    {                                                                         \
        const unsigned char* Ab = Z + (size_t)((rowstripe) * 128 + wm * 32) * 256; \
        _Pragma("unroll")                                                     \
        for (int mi = 0; mi < 2; ++mi)                                        \
            _Pragma("unroll")                                                 \
            for (int ks = 0; ks < 2; ++ks) {                                  \
                const unsigned char* pA = Ab + (size_t)(mi * 16 + l15) * 256  \
                                          + ks * 128 + quad * 32;             \
                int4v lo = *(const int4v*)pA;                                 \
                int4v hi = *(const int4v*)(pA + 16);                          \
                afr[mi][ks] = __builtin_shufflevector(lo, hi, 0,1,2,3,4,5,6,7); \
            }                                                                 \
    }
#else
    long afr[2][8];
#define LOAD_A(rowstripe)                                                     \
    {                                                                         \
        const unsigned char* Ab = Z + (size_t)((rowstripe) * 128 + wm * 32) * 256; \
        _Pragma("unroll")                                                     \
        for (int mi = 0; mi < 2; ++mi)                                        \
            _Pragma("unroll")                                                 \
            for (int kc = 0; kc < 8; ++kc)                                    \
                afr[mi][kc] = *(const long*)(Ab + (size_t)(mi * 16 + l15) * 256 \
                                             + kc * 32 + quad * 8);           \
    }
#endif

    LOAD_A(currow);
    STAGE_CHUNK(TJ_OF(u0), 0, 0);
    __syncthreads();

    const int nch = (u1 - u0) * 2;            // chunks: 2 per tile
    for (int ci = 0; ci < nch; ++ci) {
        const int ui   = u0 + (ci >> 1);
        const int half = ci & 1;
        const int buf  = ci & 1;              // alternating dbuf
        const int row  = ROW_OF(ui);
        const int tj   = TJ_OF(ui);
        if (half == 0 && row != currow) {     // crossed into row 63-p
            FLUSH_RS(currow);
            LOAD_A(row);
            currow = row;
        }
        if (ci + 1 < nch) {
            const int nui = u0 + ((ci + 1) >> 1);
            STAGE_CHUNK(TJ_OF(nui), (ci + 1) & 1, buf ^ 1);
        }

        float4v acc[2][4];
#pragma unroll
        for (int mi = 0; mi < 2; ++mi)
#pragma unroll
            for (int ni = 0; ni < 4; ++ni)
                acc[mi][ni] = (float4v){0.f, 0.f, 0.f, 0.f};

        const unsigned char* lb = &lsB[buf][0];
        __builtin_amdgcn_s_setprio(1);
#ifdef HAVE_MX
#pragma unroll
        for (int ks = 0; ks < 2; ++ks) {
            const int kp0 = ks * 8 + quad * 2;
            int8v bfv[4];
#pragma unroll
            for (int ni = 0; ni < 4; ++ni) {
                const unsigned char* pB = lb +
                    ((size_t)kp0 * 64 + ni * 16 + l15) * 16;
                int4v lo = *(const int4v*)pB;
                int4v hi = *(const int4v*)(pB + 1024);   // kp0+1 slot
                bfv[ni] = __builtin_shufflevector(lo, hi, 0,1,2,3,4,5,6,7);
            }
#pragma unroll
            for (int mi = 0; mi < 2; ++mi)
#pragma unroll
                for (int ni = 0; ni < 4; ++ni)
                    acc[mi][ni] = __builtin_amdgcn_mfma_scale_f32_16x16x128_f8f6f4(
                        afr[mi][ks], bfv[ni], acc[mi][ni],
                        0, 0,                     // cbsz=E4M3, blgp=E4M3
                        0, 0x7F7F7F7F,            // scale A = 1.0
                        0, 0x7F7F7F7F);           // scale B = 1.0
        }
#else
#pragma unroll
        for (int kc = 0; kc < 8; ++kc) {
            const int kseg = kc * 4 + quad;
            const int kp   = kseg >> 1;
            const int hf   = kseg & 1;
            long bfv[4];
#pragma unroll
            for (int ni = 0; ni < 4; ++ni)
                bfv[ni] = *(const long*)(lb +
                    ((size_t)kp * 64 + ni * 16 + l15) * 16 + hf * 8);
#pragma unroll
            for (int mi = 0; mi < 2; ++mi)
#pragma unroll
                for (int ni = 0; ni < 4; ++ni)
                    acc[mi][ni] = __builtin_amdgcn_mfma_f32_16x16x32_fp8_fp8(
                        afr[mi][kc], bfv[ni], acc[mi][ni], 0, 0, 0);
        }
#endif
        __builtin_amdgcn_s_setprio(0);

        // ---- cross tile: extract (q,q+4096) dots (raw acc, BEFORE exp)
        if (tj == row + 32) {
#pragma unroll
            for (int mi = 0; mi < 2; ++mi)
#pragma unroll
                for (int ni = 0; ni < 4; ++ni)
#pragma unroll
                    for (int reg = 0; reg < 4; ++reg) {
                        const int r  = wm * 32 + mi * 16 + quad * 4 + reg;
                        const int lc = half * 64 + ni * 16 + l15;
                        if (r == lc) dsum += acc[mi][ni][reg];
                    }
        }

        // ---- exp2 in place (acc already = 2*log2e*dot via zn8 scaling)
#pragma unroll
        for (int mi = 0; mi < 2; ++mi)
#pragma unroll
            for (int ni = 0; ni < 4; ++ni)
#pragma unroll
                for (int reg = 0; reg < 4; ++reg)
                    acc[mi][ni][reg] = EXP2F(acc[mi][ni][reg]);

        // ---- row sums accumulate in regs
#pragma unroll
        for (int mi = 0; mi < 2; ++mi)
#pragma unroll
            for (int reg = 0; reg < 4; ++reg)
                rs[mi][reg] += acc[mi][0][reg] + acc[mi][1][reg]
                             + acc[mi][2][reg] + acc[mi][3][reg];

        // ---- col sums (symmetry): per-wave 32-row partial -> own plane
        if (tj > row) {
            float* Cd = Cc + ((size_t)batch * 256 + row * 4 + wm) * 8192
                        + tj * 128 + half * 64;
#pragma unroll
            for (int ni = 0; ni < 4; ++ni) {
                float s = 0.f;
#pragma unroll
                for (int mi = 0; mi < 2; ++mi)
#pragma unroll
                    for (int reg = 0; reg < 4; ++reg)
                        s += acc[mi][ni][reg];
                s += __shfl_xor(s, 16); s += __shfl_xor(s, 32);
                if (quad == 0)
                    Cd[ni * 16 + l15] = s;
            }
        }
        __syncthreads();                      // single per-chunk barrier
    }

    FLUSH_RS(currow);

    // dv = 2*log2e * sum(d);  need -0.5*sum(d) -> factor -0.25*ln2
    {
        float dv = dsum;
        dv += __shfl_xor(dv, 1);  dv += __shfl_xor(dv, 2);
        dv += __shfl_xor(dv, 4);  dv += __shfl_xor(dv, 8);
        dv += __shfl_xor(dv, 16); dv += __shfl_xor(dv, 32);
        if (lane == 0 && dv != 0.f)
            atomicAdd(out, -0.17328680f * dv);
    }
#undef STAGE_CHUNK
#undef LOAD_A
#undef FLUSH_RS
#undef TJ_OF
#undef ROW_OF
}

// ---------------------------------------------------------------------------
// final: out += 0.125 * sum_{b,q} log(S[b][q] + sum_{r<4*(q>>7)} Cc[b][r][q] - e^2)
// grid 128 x 256 (one thread per (b,q)).  Only valid (written) planes read.
// ---------------------------------------------------------------------------
__global__ __launch_bounds__(256) void final_log_kernel(
    const float* __restrict__ S, const float* __restrict__ Cc,
    float* __restrict__ out)
{
    __shared__ float red[4];
    const int tid  = threadIdx.x;
    const int w    = tid >> 6;
    const int lane = tid & 63;
    const float E2 = 7.3890560989306495f;

    const int i = blockIdx.x * 256 + tid;     // 0..32767
    const int b = i >> 13;
    const int q = i & 8191;
    float s = S[i];
    const float* Cp = Cc + (size_t)b * 256 * 8192 + q;
    const int np = (q >> 7) * 4;              // planes 0..np-1 are written
    for (int r = 0; r < np; ++r)
        s += Cp[(size_t)r * 8192];
    float acc = logf(s - E2);

    acc += __shfl_xor(acc, 1);  acc += __shfl_xor(acc, 2);
    acc += __shfl_xor(acc, 4);  acc += __shfl_xor(acc, 8);
    acc += __shfl_xor(acc, 16); acc += __shfl_xor(acc, 32);
    if (lane == 0) red[w] = acc;
    __syncthreads();
    if (tid == 0)
        atomicAdd(out, 0.125f * (red[0] + red[1] + red[2] + red[3]));
}

// ---------------------------------------------------------------------------
// Workspace (bytes), total ~42.3 MB:
//   [0,       131072)  S (4*8192 fp32)
//   [131072,  262144)  W1bf
//   [262144,  393216)  W2bf
//   [393216,  8781824) zn8 (fp8, 8.39MB)
//   [8781824, 42336256) Cc (col-sum planes, 4*256*8192 fp32 = 33.55MB;
//                      no memset: final reads only written planes)
// ---------------------------------------------------------------------------
extern "C" void kernel_launch(void* const* d_in, const int* in_sizes, int n_in,
                              void* d_out, int out_size, void* d_ws, size_t ws_size,
                              hipStream_t stream)
{
    const float* X1 = (const float*)d_in[0];
    const float* X2 = (const float*)d_in[1];
    const float* W1 = (const float*)d_in[2];
    const float* b1 = (const float*)d_in[3];
    const float* W2 = (const float*)d_in[4];
    const float* b2 = (const float*)d_in[5];

    char* ws = (char*)d_ws;
    float* S    = (float*)(ws + 0);
    short* W1bf = (short*)(ws + 131072);
    short* W2bf = (short*)(ws + 262144);
    unsigned char* zn8 = (unsigned char*)(ws + 393216);
    float* Cc   = (float*)(ws + 8781824);

    convW_zero_kernel<<<128, 256, 0, stream>>>(W1, W2, W1bf, W2bf,
                                               S, (float*)d_out);
    fusedproj_kernel<<<1024, 256, 0, stream>>>(X1, X2, W1bf, b1, W2bf, b2, zn8);
    gram_fp8_sym_kernel<<<1024, 256, 0, stream>>>(zn8, S, Cc, (float*)d_out);
    final_log_kernel<<<128, 256, 0, stream>>>(S, Cc, (float*)d_out);
}

// Round 9
// 230.229 us; speedup vs baseline: 1.5978x; 1.0417x over previous
//
#include <hip/hip_runtime.h>
#include <math.h>

// ---------------------------------------------------------------------------
// Problem: B=4, L=4096, D=P=256, tau=0.5
// out = (1/8) * sum_{b,l} [ log(S1-e^2) + log(S2-e^2) - 4*d[b,l] ]
//   S[b,q] = sum_{m<2L} exp(2 * Zhat[b,q].Zhat[b,m]),  Zhat = [z1n; z2n]
// R20: barrier-free gram at 4 blocks/CU.  R19 postmortem: __syncthreads
// drains vmcnt(0) including the dbuf prefetch -> per-chunk full drain is
// the bottleneck (doubling nominal occupancy didn't help).  R17's no-LDS
// no-barrier gram (VGPR 120 <= 128) failed only on wave count (512 blocks
// = 2 blocks/CU); this round runs the IDENTICAL R17 gram geometry
// (2wm x 2wn 64x64 waves, direct global B-frags) on a 1024-block grid
// (pairs split into eighths) -> 4 blocks/CU = 16 waves/CU, zero barriers.
// fusedproj/convW/final = R17 exact (single-variable change).
// ---------------------------------------------------------------------------

typedef __attribute__((ext_vector_type(8))) short short8;
typedef __attribute__((ext_vector_type(4))) short short4v;
typedef __attribute__((ext_vector_type(4))) float float4v;
typedef __attribute__((ext_vector_type(8))) int int8v;
typedef __attribute__((ext_vector_type(4))) int int4v;

#if defined(__has_builtin)
#if __has_builtin(__builtin_amdgcn_exp2f)
#define EXP2F(x) __builtin_amdgcn_exp2f(x)
#endif
#endif
#ifndef EXP2F
#define EXP2F(x) __expf(0.69314718056f * (x))
#endif

__device__ __forceinline__ short f2bf(float f) {
    unsigned u = __builtin_bit_cast(unsigned, f);
    u += 0x7fffu + ((u >> 16) & 1u);          // RNE
    return (short)(u >> 16);
}

// manual fp32 -> fp8 e4m3fn (OCP), RNE.  |f| <= ~1.7 here.
__device__ __forceinline__ unsigned char f2fp8(float f) {
    float af = fabsf(f);
    unsigned s = (__builtin_bit_cast(unsigned, f) >> 31) << 7;
    if (af < 0.015625f) {                     // subnormal (<2^-6); 8 rolls up
        int q = (int)rintf(af * 512.0f);
        return (unsigned char)(s | (unsigned)q);
    }
    unsigned au = __builtin_bit_cast(unsigned, af);
    au += 0x7FFFFu + ((au >> 20) & 1u);       // RNE at bit 20
    int e = (int)(au >> 23) - 127;
    unsigned m = (au >> 20) & 7u;
    return (unsigned char)(s | (unsigned)((e + 7) << 3) | m);
}

__device__ __forceinline__ void gl_lds16(const void* g, void* l) {
    __builtin_amdgcn_global_load_lds(
        (const __attribute__((address_space(1))) void*)g,
        (__attribute__((address_space(3))) void*)l, 16, 0, 0);
}

// ---------------------------------------------------------------------------
// convW + zero: W1/W2 fp32 -> bf16 and zero S + out.  grid 128 x 256.
// ---------------------------------------------------------------------------
__global__ __launch_bounds__(256) void convW_zero_kernel(
    const float* __restrict__ W1, const float* __restrict__ W2,
    short* __restrict__ d1, short* __restrict__ d2,
    float* __restrict__ S, float* __restrict__ out)
{
    int i = blockIdx.x * 256 + threadIdx.x;   // 0..32767
    const float* src = (i < 16384) ? W1 : W2;
    short* dst = (i < 16384) ? d1 : d2;
    int j = i & 16383;
    float4v v = ((const float4v*)src)[j];
    short4v o;
    o.x = f2bf(v.x); o.y = f2bf(v.y); o.z = f2bf(v.z); o.w = f2bf(v.w);
    ((short4v*)dst)[j] = o;
    S[i] = 0.f;
    if (i == 0) *out = 0.f;
}

// ---------------------------------------------------------------------------
// fused proj (R17 exact): per 64-row block:
//   phase1: acc = X*W1^T  (A-frags from X fp32 global, f2bf in-register;
//           W1 bf16 staged in lsB) -> +b1, elu -> bf16 -> lsH
//   phase2: acc = H*W2^T (A-frags from lsH, W2 staged per kt)
//   epilogue: +b2, rownorm -> zn8 = fp8(sqrt(2*log2e)*z/||z||)
// grid 512 x 256thr.  LDS ~66KB -> 2 blocks/CU.
// ---------------------------------------------------------------------------
__global__ __launch_bounds__(256, 2) void fusedproj_kernel(
    const float* __restrict__ X1, const float* __restrict__ X2,
    const short* __restrict__ W1bf, const float* __restrict__ b1,
    const short* __restrict__ W2bf, const float* __restrict__ b2,
    unsigned char* __restrict__ zn8)
{
    __shared__ short lsB[16384];   // 32KB W1/W2 staging
    __shared__ short lsH[16384];   // 32KB H, staged layout
    __shared__ float rssq[4][64];
    __shared__ float rinv[64];

    const int arow0 = blockIdx.x * 64;
    const int tid  = threadIdx.x;
    const int w    = tid >> 6;
    const int lane = tid & 63;
    const int quad = lane >> 4;
    const int l15  = lane & 15;

    const int set = arow0 >> 14;
    const float* Xs = (set ? X2 : X1) + (size_t)(arow0 & 16383) * 256;

    float4v acc[4][4];
#pragma unroll
    for (int mi = 0; mi < 4; ++mi)
#pragma unroll
        for (int ni = 0; ni < 4; ++ni)
            acc[mi][ni] = (float4v){0.f, 0.f, 0.f, 0.f};

    // ---- phase 1: X * W1^T  (X fp32 -> bf16 in-register)
    for (int kt = 0; kt < 4; ++kt) {
        const int kbase = kt * 64;
#pragma unroll
        for (int r = 0; r < 8; ++r) {
            const int c   = w * 8 + r;        // 32 chunks of W1
            const int s   = c * 64 + lane;
            const int kc  = s >> 8;
            const int row = s & 255;
            gl_lds16(W1bf + (size_t)row * 256 + kbase + kc * 8,
                     lsB + (size_t)c * 512);
        }
        __syncthreads();
#pragma unroll
        for (int ks = 0; ks < 2; ++ks) {
            const int kc = ks * 4 + quad;
            short8 af[4], bfv[4];
#pragma unroll
            for (int mi = 0; mi < 4; ++mi) {
                const float* xp = Xs + (size_t)(mi * 16 + l15) * 256
                                  + kbase + kc * 8;
                float4v a0 = *(const float4v*)xp;
                float4v a1 = *(const float4v*)(xp + 4);
                short8 t;
                t[0] = f2bf(a0.x); t[1] = f2bf(a0.y);
                t[2] = f2bf(a0.z); t[3] = f2bf(a0.w);
                t[4] = f2bf(a1.x); t[5] = f2bf(a1.y);
                t[6] = f2bf(a1.z); t[7] = f2bf(a1.w);
                af[mi] = t;
            }
#pragma unroll
            for (int ni = 0; ni < 4; ++ni)
                bfv[ni] = *(const short8*)(lsB +
                    ((size_t)kc * 256 + w * 64 + ni * 16 + l15) * 8);
#pragma unroll
            for (int mi = 0; mi < 4; ++mi)
#pragma unroll
                for (int ni = 0; ni < 4; ++ni)
                    acc[mi][ni] = __builtin_amdgcn_mfma_f32_16x16x32_bf16(
                        af[mi], bfv[ni], acc[mi][ni], 0, 0, 0);
        }
        __syncthreads();
    }

    // ---- epilogue 1: +b1, elu, bf16 -> lsH  (local rows 0..63)
    {
        const int rowbase = quad * 4;
        const int colbase = w * 64 + l15;
#pragma unroll
        for (int ni = 0; ni < 4; ++ni) {
            const int p  = colbase + ni * 16;
            const float bv = b1[p];
#pragma unroll
            for (int mi = 0; mi < 4; ++mi)
#pragma unroll
                for (int reg = 0; reg < 4; ++reg) {
                    const int row = rowbase + mi * 16 + reg;
                    float v = acc[mi][ni][reg] + bv;
                    v = (v > 0.f) ? v : expm1f(v);
                    lsH[(size_t)(p >> 3) * 512 + row * 8 + (p & 7)] = f2bf(v);
                }
        }
    }

    // ---- phase 2: H * W2^T  (A from lsH, B = W2 staged per kt)
#pragma unroll
    for (int mi = 0; mi < 4; ++mi)
#pragma unroll
        for (int ni = 0; ni < 4; ++ni)
            acc[mi][ni] = (float4v){0.f, 0.f, 0.f, 0.f};

    for (int kt = 0; kt < 4; ++kt) {
        const int kbase = kt * 64;
#pragma unroll
        for (int r = 0; r < 8; ++r) {
            const int c   = w * 8 + r;        // 0..31 chunks, all B
            const int s   = c * 64 + lane;
            const int kc  = s >> 8;
            const int row = s & 255;
            gl_lds16(W2bf + (size_t)row * 256 + kbase + kc * 8,
                     lsB + (size_t)c * 512);
        }
        __syncthreads();                      // kt=0: also guards lsH writes
#pragma unroll
        for (int ks = 0; ks < 2; ++ks) {
            const int kc = ks * 4 + quad;
            short8 af[4], bfv[4];
#pragma unroll
            for (int mi = 0; mi < 4; ++mi)
                af[mi] = *(const short8*)(lsH +
                    ((size_t)(kt * 8 + kc) * 64 + mi * 16 + l15) * 8);
#pragma unroll
            for (int ni = 0; ni < 4; ++ni)
                bfv[ni] = *(const short8*)(lsB +
                    ((size_t)kc * 256 + w * 64 + ni * 16 + l15) * 8);
#pragma unroll
            for (int mi = 0; mi < 4; ++mi)
#pragma unroll
                for (int ni = 0; ni < 4; ++ni)
                    acc[mi][ni] = __builtin_amdgcn_mfma_f32_16x16x32_bf16(
                        af[mi], bfv[ni], acc[mi][ni], 0, 0, 0);
        }
        __syncthreads();
    }

    // ---- epilogue 2: +b2, normalize, fp8 out (sqrt(2*log2e) folded)
#pragma unroll
    for (int ni = 0; ni < 4; ++ni) {
        const float bv = b2[w * 64 + ni * 16 + l15];
#pragma unroll
        for (int mi = 0; mi < 4; ++mi)
#pragma unroll
            for (int reg = 0; reg < 4; ++reg)
                acc[mi][ni][reg] += bv;
    }
    float ps[4][4];
#pragma unroll
    for (int mi = 0; mi < 4; ++mi)
#pragma unroll
        for (int reg = 0; reg < 4; ++reg) {
            float s = 0.f;
#pragma unroll
            for (int ni = 0; ni < 4; ++ni) {
                float v = acc[mi][ni][reg];
                s += v * v;
            }
            s += __shfl_xor(s, 1); s += __shfl_xor(s, 2);
            s += __shfl_xor(s, 4); s += __shfl_xor(s, 8);
            ps[mi][reg] = s;
        }
    if (l15 == 0) {
#pragma unroll
        for (int mi = 0; mi < 4; ++mi)
#pragma unroll
            for (int reg = 0; reg < 4; ++reg)
                rssq[w][mi * 16 + quad * 4 + reg] = ps[mi][reg];
    }
    __syncthreads();
    if (tid < 64) {
        float ssq = rssq[0][tid] + rssq[1][tid] + rssq[2][tid] + rssq[3][tid];
        rinv[tid] = 1.69864360f / fmaxf(sqrtf(ssq), 1e-12f);
    }
    __syncthreads();

    const int r0  = arow0;                 // multiple of 64
    const int bb  = (r0 >> 12) & 3;
    const int l0  = r0 & 4095;
    unsigned char* dst = zn8 + ((size_t)(bb * 2 + set) * 4096 + l0) * 256;
    const int colbase = w * 64 + l15;
#pragma unroll
    for (int mi = 0; mi < 4; ++mi)
#pragma unroll
        for (int reg = 0; reg < 4; ++reg) {
            const int rl = mi * 16 + quad * 4 + reg;
            const float inv = rinv[rl];
#pragma unroll
            for (int ni = 0; ni < 4; ++ni)
                dst[(size_t)rl * 256 + colbase + ni * 16] =
                    f2fp8(acc[mi][ni][reg] * inv);
        }
}

// ---------------------------------------------------------------------------
// FP8 symmetric flash-gram R20 (no-LDS, no-barrier): grid 1024 x 256thr
// (4 waves: 2wm x 2wn, wave = 64 rows x 64 cols — R17 geometry, VGPR ~120
// -> 4 blocks/CU = 16 waves/CU).  Block = (batch, pair p, eighth e); pair
// = row-stripes {p, 63-p}, 65 tiles (9/8x7).  A-frags AND B-frags direct
// from global (Z L2-resident; B rows L1-shared by the wm-pair).  Row-sums
// in regs -> atomic flush per stripe.  Col-sums (symmetry) per off-diag
// tile -> non-atomic store into plane Cc[batch][2*row+wm][8192].
// Cross tiles (tj==row+32): d-dot extraction before exp.
// ---------------------------------------------------------------------------
#if defined(__has_builtin)
#if __has_builtin(__builtin_amdgcn_mfma_scale_f32_16x16x128_f8f6f4)
#define HAVE_MX 1
#endif
#endif

__global__ __launch_bounds__(256, 2) void gram_fp8_sym_kernel(
    const unsigned char* __restrict__ zn8, float* __restrict__ S,
    float* __restrict__ Cc, float* __restrict__ out)
{
    const int bx    = blockIdx.x;             // 0..1023
    const int xcd   = bx & 7;                 // batch -> XCD pair {2b,2b+1}
    const int batch = xcd >> 1;
    const int sub   = (bx >> 3) * 2 + (xcd & 1);   // 0..255
    const int p     = sub >> 3;               // pair 0..31
    const int e     = sub & 7;                // eighth
    const int u0    = (e == 0) ? 0 : 9 + (e - 1) * 8;
    const int u1    = u0 + ((e == 0) ? 9 : 8);
    const int ubrk  = 64 - p;                 // first tile index of row 63-p

    const unsigned char* Z = zn8 + (size_t)batch * 2097152;

    const int tid  = threadIdx.x;
    const int w    = tid >> 6;
    const int lane = tid & 63;
    const int wm   = w & 1;                   // 64-row band
    const int wn   = w >> 1;                  // 64-col band
    const int quad = lane >> 4;
    const int l15  = lane & 15;

#define TJ_OF(u)  ((u) < ubrk ? p + (u) : (u) - 1)
#define ROW_OF(u) ((u) < ubrk ? p : 63 - p)

    float rs[4][4];
#pragma unroll
    for (int mi = 0; mi < 4; ++mi)
#pragma unroll
        for (int reg = 0; reg < 4; ++reg)
            rs[mi][reg] = 0.f;
    float dsum = 0.f;

#define FLUSH_RS(rowstripe)                                                   \
    {                                                                         \
        float* Sr = S + (size_t)batch * 8192 + (rowstripe) * 128 + wm * 64;   \
        _Pragma("unroll")                                                     \
        for (int mi = 0; mi < 4; ++mi)                                        \
            _Pragma("unroll")                                                 \
            for (int reg = 0; reg < 4; ++reg) {                               \
                float v = rs[mi][reg];                                        \
                v += __shfl_xor(v, 1); v += __shfl_xor(v, 2);                 \
                v += __shfl_xor(v, 4); v += __shfl_xor(v, 8);                 \
                if (l15 == 0)                                                 \
                    atomicAdd(&Sr[mi * 16 + quad * 4 + reg], v);              \
                rs[mi][reg] = 0.f;                                            \
            }                                                                 \
    }

    int currow = ROW_OF(u0);

#ifdef HAVE_MX
    int8v afr[4][2];
#define LOAD_A(rowstripe)                                                     \
    {                                                                         \
        const unsigned char* Ab = Z + (size_t)((rowstripe) * 128 + wm * 64) * 256; \
        _Pragma("unroll")                                                     \
        for (int mi = 0; mi < 4; ++mi)                                        \
            _Pragma("unroll")                                                 \
            for (int ks = 0; ks < 2; ++ks) {                                  \
                const unsigned char* pA = Ab + (size_t)(mi * 16 + l15) * 256  \
                                          + ks * 128 + quad * 32;             \
                int4v lo = *(const int4v*)pA;                                 \
                int4v hi = *(const int4v*)(pA + 16);                          \
                afr[mi][ks] = __builtin_shufflevector(lo, hi, 0,1,2,3,4,5,6,7); \
            }                                                                 \
    }
#else
    long afr[4][8];
#define LOAD_A(rowstripe)                                                     \
    {                                                                         \
        const unsigned char* Ab = Z + (size_t)((rowstripe) * 128 + wm * 64) * 256; \
        _Pragma("unroll")                                                     \
        for (int mi = 0; mi < 4; ++mi)                                        \
            _Pragma("unroll")                                                 \
            for (int kc = 0; kc < 8; ++kc)                                    \
                afr[mi][kc] = *(const long*)(Ab + (size_t)(mi * 16 + l15) * 256 \
                                             + kc * 32 + quad * 8);           \
    }
#endif

    LOAD_A(currow);

    for (int ui = u0; ui < u1; ++ui) {
        const int row = ROW_OF(ui);
        const int tj  = TJ_OF(ui);
        if (row != currow) {                  // crossed into row 63-p
            FLUSH_RS(currow);
            LOAD_A(row);
            currow = row;
        }

        // B frags direct from global: rows (tj*128 + wn*64 + ni*16 + l15)
        const unsigned char* Bb = Z + ((size_t)tj * 128 + wn * 64) * 256;

        float4v acc[4][4];
#pragma unroll
        for (int mi = 0; mi < 4; ++mi)
#pragma unroll
            for (int ni = 0; ni < 4; ++ni)
                acc[mi][ni] = (float4v){0.f, 0.f, 0.f, 0.f};

#ifdef HAVE_MX
        int8v bfv[2][4];
#pragma unroll
        for (int ks = 0; ks < 2; ++ks)
#pragma unroll
            for (int ni = 0; ni < 4; ++ni) {
                const unsigned char* pB = Bb + (size_t)(ni * 16 + l15) * 256
                                          + ks * 128 + quad * 32;
                int4v lo = *(const int4v*)pB;
                int4v hi = *(const int4v*)(pB + 16);
                bfv[ks][ni] = __builtin_shufflevector(lo, hi, 0,1,2,3,4,5,6,7);
            }
        __builtin_amdgcn_s_setprio(1);
#pragma unroll
        for (int ks = 0; ks < 2; ++ks)
#pragma unroll
            for (int mi = 0; mi < 4; ++mi)
#pragma unroll
                for (int ni = 0; ni < 4; ++ni)
                    acc[mi][ni] = __builtin_amdgcn_mfma_scale_f32_16x16x128_f8f6f4(
                        afr[mi][ks], bfv[ks][ni], acc[mi][ni],
                        0, 0,                     // cbsz=E4M3, blgp=E4M3
                        0, 0x7F7F7F7F,            // scale A = 1.0
                        0, 0x7F7F7F7F);           // scale B = 1.0
        __builtin_amdgcn_s_setprio(0);
#else
#pragma unroll
        for (int kc = 0; kc < 8; ++kc) {
            long bfv[4];
#pragma unroll
            for (int ni = 0; ni < 4; ++ni)
                bfv[ni] = *(const long*)(Bb + (size_t)(ni * 16 + l15) * 256
                                         + kc * 32 + quad * 8);
#pragma unroll
            for (int mi = 0; mi < 4; ++mi)
#pragma unroll
                for (int ni = 0; ni < 4; ++ni)
                    acc[mi][ni] = __builtin_amdgcn_mfma_f32_16x16x32_fp8_fp8(
                        afr[mi][kc], bfv[ni], acc[mi][ni], 0, 0, 0);
        }
#endif

        // ---- cross tile: extract (q,q+4096) dots (raw acc, BEFORE exp)
        if (tj == row + 32) {
#pragma unroll
            for (int mi = 0; mi < 4; ++mi)
#pragma unroll
                for (int ni = 0; ni < 4; ++ni)
#pragma unroll
                    for (int reg = 0; reg < 4; ++reg) {
                        const int r = wm * 64 + mi * 16 + quad * 4 + reg;
                        const int c = wn * 64 + ni * 16 + l15;
                        if (r == c) dsum += acc[mi][ni][reg];
                    }
        }

        // ---- exp2 in place (acc already = 2*log2e*dot via zn8 scaling)
#pragma unroll
        for (int mi = 0; mi < 4; ++mi)
#pragma unroll
            for (int ni = 0; ni < 4; ++ni)
#pragma unroll
                for (int reg = 0; reg < 4; ++reg)
                    acc[mi][ni][reg] = EXP2F(acc[mi][ni][reg]);

        // ---- row sums accumulate in regs
#pragma unroll
        for (int mi = 0; mi < 4; ++mi)
#pragma unroll
            for (int reg = 0; reg < 4; ++reg)
                rs[mi][reg] += acc[mi][0][reg] + acc[mi][1][reg]
                             + acc[mi][2][reg] + acc[mi][3][reg];

        // ---- col sums (symmetry): per-wave 64-row partial -> own plane
        if (tj > row) {
            float* Cd = Cc + ((size_t)batch * 128 + row * 2 + wm) * 8192
                        + tj * 128 + wn * 64;
#pragma unroll
            for (int ni = 0; ni < 4; ++ni) {
                float s = 0.f;
#pragma unroll
                for (int mi = 0; mi < 4; ++mi)
#pragma unroll
                    for (int reg = 0; reg < 4; ++reg)
                        s += acc[mi][ni][reg];
                s += __shfl_xor(s, 16); s += __shfl_xor(s, 32);
                if (quad == 0)
                    Cd[ni * 16 + l15] = s;
            }
        }
    }

    FLUSH_RS(currow);

    // dv = 2*log2e * sum(d);  need -0.5*sum(d) -> factor -0.25*ln2
    {
        float dv = dsum;
        dv += __shfl_xor(dv, 1);  dv += __shfl_xor(dv, 2);
        dv += __shfl_xor(dv, 4);  dv += __shfl_xor(dv, 8);
        dv += __shfl_xor(dv, 16); dv += __shfl_xor(dv, 32);
        if (lane == 0 && dv != 0.f)
            atomicAdd(out, -0.17328680f * dv);
    }
#undef LOAD_A
#undef FLUSH_RS
#undef TJ_OF
#undef ROW_OF
}

// ---------------------------------------------------------------------------
// final: out += 0.125 * sum_{b,q} log(S[b][q] + sum_{r<2*(q>>7)} Cc[b][r][q] - e^2)
// grid 128 x 256 (one thread per (b,q)).  Only valid (written) planes read.
// ---------------------------------------------------------------------------
__global__ __launch_bounds__(256) void final_log_kernel(
    const float* __restrict__ S, const float* __restrict__ Cc,
    float* __restrict__ out)
{
    __shared__ float red[4];
    const int tid  = threadIdx.x;
    const int w    = tid >> 6;
    const int lane = tid & 63;
    const float E2 = 7.3890560989306495f;

    const int i = blockIdx.x * 256 + tid;     // 0..32767
    const int b = i >> 13;
    const int q = i & 8191;
    float s = S[i];
    const float* Cp = Cc + (size_t)b * 128 * 8192 + q;
    const int np = (q >> 7) * 2;              // planes 0..np-1 are written
    for (int r = 0; r < np; ++r)
        s += Cp[(size_t)r * 8192];
    float acc = logf(s - E2);

    acc += __shfl_xor(acc, 1);  acc += __shfl_xor(acc, 2);
    acc += __shfl_xor(acc, 4);  acc += __shfl_xor(acc, 8);
    acc += __shfl_xor(acc, 16); acc += __shfl_xor(acc, 32);
    if (lane == 0) red[w] = acc;
    __syncthreads();
    if (tid == 0)
        atomicAdd(out, 0.125f * (red[0] + red[1] + red[2] + red[3]));
}

// ---------------------------------------------------------------------------
// Workspace (bytes), total ~25.6 MB:
//   [0,       131072)  S (4*8192 fp32)
//   [131072,  262144)  W1bf
//   [262144,  393216)  W2bf
//   [393216,  8781824) zn8 (fp8, 8.39MB)
//   [8781824, 25559040) Cc (col-sum planes, 4*128*8192 fp32 = 16.78MB;
//                      no memset: final reads only written planes)
// ---------------------------------------------------------------------------
extern "C" void kernel_launch(void* const* d_in, const int* in_sizes, int n_in,
                              void* d_out, int out_size, void* d_ws, size_t ws_size,
                              hipStream_t stream)
{
    const float* X1 = (const float*)d_in[0];
    const float* X2 = (const float*)d_in[1];
    const float* W1 = (const float*)d_in[2];
    const float* b1 = (const float*)d_in[3];
    const float* W2 = (const float*)d_in[4];
    const float* b2 = (const float*)d_in[5];

    char* ws = (char*)d_ws;
    float* S    = (float*)(ws + 0);
    short* W1bf = (short*)(ws + 131072);
    short* W2bf = (short*)(ws + 262144);
    unsigned char* zn8 = (unsigned char*)(ws + 393216);
    float* Cc   = (float*)(ws + 8781824);

    convW_zero_kernel<<<128, 256, 0, stream>>>(W1, W2, W1bf, W2bf,
                                               S, (float*)d_out);
    fusedproj_kernel<<<512, 256, 0, stream>>>(X1, X2, W1bf, b1, W2bf, b2, zn8);
    gram_fp8_sym_kernel<<<1024, 256, 0, stream>>>(zn8, S, Cc, (float*)d_out);
    final_log_kernel<<<128, 256, 0, stream>>>(S, Cc, (float*)d_out);
}

// Round 10
// 212.461 us; speedup vs baseline: 1.7314x; 1.0836x over previous
//
#include <hip/hip_runtime.h>
#include <math.h>

// ---------------------------------------------------------------------------
// Problem: B=4, L=4096, D=P=256, tau=0.5
// out = (1/8) * sum_{b,l} [ log(S1-e^2) + log(S2-e^2) - 4*d[b,l] ]
//   S[b,q] = sum_{m<2L} exp(2 * Zhat[b,q].Zhat[b,m]),  Zhat = [z1n; z2n]
// R21: recombination of measured-best components.  R20 postmortem: the
// occupancy cap was never grid geometry — acc AGPRs share the unified reg
// file (arch 120 + acc 64 ~ 184/wave -> 2 waves/SIMD, always).  So pick
// the best measured variant of each kernel:
//  - convW_zero (R17+): ~5 us.
//  - fusedproj (R17/R20 direct-X, verbatim): 89 us measured.
//  - gram (R16 dbuf-LDS 512-block, verbatim): 67.3 us measured — beats
//    no-LDS (77-87) and chunked (76) at the same 2 waves/SIMD because the
//    1-deep gl_lds16 prefetch overlaps the MFMA+epilogue window.
//  - final_log (np = (q>>7)*2 planes).
// ---------------------------------------------------------------------------

typedef __attribute__((ext_vector_type(8))) short short8;
typedef __attribute__((ext_vector_type(4))) short short4v;
typedef __attribute__((ext_vector_type(4))) float float4v;
typedef __attribute__((ext_vector_type(8))) int int8v;
typedef __attribute__((ext_vector_type(4))) int int4v;

#if defined(__has_builtin)
#if __has_builtin(__builtin_amdgcn_exp2f)
#define EXP2F(x) __builtin_amdgcn_exp2f(x)
#endif
#endif
#ifndef EXP2F
#define EXP2F(x) __expf(0.69314718056f * (x))
#endif

__device__ __forceinline__ short f2bf(float f) {
    unsigned u = __builtin_bit_cast(unsigned, f);
    u += 0x7fffu + ((u >> 16) & 1u);          // RNE
    return (short)(u >> 16);
}

// manual fp32 -> fp8 e4m3fn (OCP), RNE.  |f| <= ~1.7 here.
__device__ __forceinline__ unsigned char f2fp8(float f) {
    float af = fabsf(f);
    unsigned s = (__builtin_bit_cast(unsigned, f) >> 31) << 7;
    if (af < 0.015625f) {                     // subnormal (<2^-6); 8 rolls up
        int q = (int)rintf(af * 512.0f);
        return (unsigned char)(s | (unsigned)q);
    }
    unsigned au = __builtin_bit_cast(unsigned, af);
    au += 0x7FFFFu + ((au >> 20) & 1u);       // RNE at bit 20
    int e = (int)(au >> 23) - 127;
    unsigned m = (au >> 20) & 7u;
    return (unsigned char)(s | (unsigned)((e + 7) << 3) | m);
}

__device__ __forceinline__ void gl_lds16(const void* g, void* l) {
    __builtin_amdgcn_global_load_lds(
        (const __attribute__((address_space(1))) void*)g,
        (__attribute__((address_space(3))) void*)l, 16, 0, 0);
}

// ---------------------------------------------------------------------------
// convW + zero: W1/W2 fp32 -> bf16 and zero S + out.  grid 128 x 256.
// ---------------------------------------------------------------------------
__global__ __launch_bounds__(256) void convW_zero_kernel(
    const float* __restrict__ W1, const float* __restrict__ W2,
    short* __restrict__ d1, short* __restrict__ d2,
    float* __restrict__ S, float* __restrict__ out)
{
    int i = blockIdx.x * 256 + threadIdx.x;   // 0..32767
    const float* src = (i < 16384) ? W1 : W2;
    short* dst = (i < 16384) ? d1 : d2;
    int j = i & 16383;
    float4v v = ((const float4v*)src)[j];
    short4v o;
    o.x = f2bf(v.x); o.y = f2bf(v.y); o.z = f2bf(v.z); o.w = f2bf(v.w);
    ((short4v*)dst)[j] = o;
    S[i] = 0.f;
    if (i == 0) *out = 0.f;
}

// ---------------------------------------------------------------------------
// fused proj (R17/R20 exact, 89us measured): per 64-row block:
//   phase1: acc = X*W1^T  (A-frags from X fp32 global, f2bf in-register;
//           W1 bf16 staged in lsB) -> +b1, elu -> bf16 -> lsH
//   phase2: acc = H*W2^T (A-frags from lsH, W2 staged per kt)
//   epilogue: +b2, rownorm -> zn8 = fp8(sqrt(2*log2e)*z/||z||)
// grid 512 x 256thr.  LDS ~66KB -> 2 blocks/CU.
// ---------------------------------------------------------------------------
__global__ __launch_bounds__(256, 2) void fusedproj_kernel(
    const float* __restrict__ X1, const float* __restrict__ X2,
    const short* __restrict__ W1bf, const float* __restrict__ b1,
    const short* __restrict__ W2bf, const float* __restrict__ b2,
    unsigned char* __restrict__ zn8)
{
    __shared__ short lsB[16384];   // 32KB W1/W2 staging
    __shared__ short lsH[16384];   // 32KB H, staged layout
    __shared__ float rssq[4][64];
    __shared__ float rinv[64];

    const int arow0 = blockIdx.x * 64;
    const int tid  = threadIdx.x;
    const int w    = tid >> 6;
    const int lane = tid & 63;
    const int quad = lane >> 4;
    const int l15  = lane & 15;

    const int set = arow0 >> 14;
    const float* Xs = (set ? X2 : X1) + (size_t)(arow0 & 16383) * 256;

    float4v acc[4][4];
#pragma unroll
    for (int mi = 0; mi < 4; ++mi)
#pragma unroll
        for (int ni = 0; ni < 4; ++ni)
            acc[mi][ni] = (float4v){0.f, 0.f, 0.f, 0.f};

    // ---- phase 1: X * W1^T  (X fp32 -> bf16 in-register)
    for (int kt = 0; kt < 4; ++kt) {
        const int kbase = kt * 64;
#pragma unroll
        for (int r = 0; r < 8; ++r) {
            const int c   = w * 8 + r;        // 32 chunks of W1
            const int s   = c * 64 + lane;
            const int kc  = s >> 8;
            const int row = s & 255;
            gl_lds16(W1bf + (size_t)row * 256 + kbase + kc * 8,
                     lsB + (size_t)c * 512);
        }
        __syncthreads();
#pragma unroll
        for (int ks = 0; ks < 2; ++ks) {
            const int kc = ks * 4 + quad;
            short8 af[4], bfv[4];
#pragma unroll
            for (int mi = 0; mi < 4; ++mi) {
                const float* xp = Xs + (size_t)(mi * 16 + l15) * 256
                                  + kbase + kc * 8;
                float4v a0 = *(const float4v*)xp;
                float4v a1 = *(const float4v*)(xp + 4);
                short8 t;
                t[0] = f2bf(a0.x); t[1] = f2bf(a0.y);
                t[2] = f2bf(a0.z); t[3] = f2bf(a0.w);
                t[4] = f2bf(a1.x); t[5] = f2bf(a1.y);
                t[6] = f2bf(a1.z); t[7] = f2bf(a1.w);
                af[mi] = t;
            }
#pragma unroll
            for (int ni = 0; ni < 4; ++ni)
                bfv[ni] = *(const short8*)(lsB +
                    ((size_t)kc * 256 + w * 64 + ni * 16 + l15) * 8);
#pragma unroll
            for (int mi = 0; mi < 4; ++mi)
#pragma unroll
                for (int ni = 0; ni < 4; ++ni)
                    acc[mi][ni] = __builtin_amdgcn_mfma_f32_16x16x32_bf16(
                        af[mi], bfv[ni], acc[mi][ni], 0, 0, 0);
        }
        __syncthreads();
    }

    // ---- epilogue 1: +b1, elu, bf16 -> lsH  (local rows 0..63)
    {
        const int rowbase = quad * 4;
        const int colbase = w * 64 + l15;
#pragma unroll
        for (int ni = 0; ni < 4; ++ni) {
            const int p  = colbase + ni * 16;
            const float bv = b1[p];
#pragma unroll
            for (int mi = 0; mi < 4; ++mi)
#pragma unroll
                for (int reg = 0; reg < 4; ++reg) {
                    const int row = rowbase + mi * 16 + reg;
                    float v = acc[mi][ni][reg] + bv;
                    v = (v > 0.f) ? v : expm1f(v);
                    lsH[(size_t)(p >> 3) * 512 + row * 8 + (p & 7)] = f2bf(v);
                }
        }
    }

    // ---- phase 2: H * W2^T  (A from lsH, B = W2 staged per kt)
#pragma unroll
    for (int mi = 0; mi < 4; ++mi)
#pragma unroll
        for (int ni = 0; ni < 4; ++ni)
            acc[mi][ni] = (float4v){0.f, 0.f, 0.f, 0.f};

    for (int kt = 0; kt < 4; ++kt) {
        const int kbase = kt * 64;
#pragma unroll
        for (int r = 0; r < 8; ++r) {
            const int c   = w * 8 + r;        // 0..31 chunks, all B
            const int s   = c * 64 + lane;
            const int kc  = s >> 8;
            const int row = s & 255;
            gl_lds16(W2bf + (size_t)row * 256 + kbase + kc * 8,
                     lsB + (size_t)c * 512);
        }
        __syncthreads();                      // kt=0: also guards lsH writes
#pragma unroll
        for (int ks = 0; ks < 2; ++ks) {
            const int kc = ks * 4 + quad;
            short8 af[4], bfv[4];
#pragma unroll
            for (int mi = 0; mi < 4; ++mi)
                af[mi] = *(const short8*)(lsH +
                    ((size_t)(kt * 8 + kc) * 64 + mi * 16 + l15) * 8);
#pragma unroll
            for (int ni = 0; ni < 4; ++ni)
                bfv[ni] = *(const short8*)(lsB +
                    ((size_t)kc * 256 + w * 64 + ni * 16 + l15) * 8);
#pragma unroll
            for (int mi = 0; mi < 4; ++mi)
#pragma unroll
                for (int ni = 0; ni < 4; ++ni)
                    acc[mi][ni] = __builtin_amdgcn_mfma_f32_16x16x32_bf16(
                        af[mi], bfv[ni], acc[mi][ni], 0, 0, 0);
        }
        __syncthreads();
    }

    // ---- epilogue 2: +b2, normalize, fp8 out (sqrt(2*log2e) folded)
#pragma unroll
    for (int ni = 0; ni < 4; ++ni) {
        const float bv = b2[w * 64 + ni * 16 + l15];
#pragma unroll
        for (int mi = 0; mi < 4; ++mi)
#pragma unroll
            for (int reg = 0; reg < 4; ++reg)
                acc[mi][ni][reg] += bv;
    }
    float ps[4][4];
#pragma unroll
    for (int mi = 0; mi < 4; ++mi)
#pragma unroll
        for (int reg = 0; reg < 4; ++reg) {
            float s = 0.f;
#pragma unroll
            for (int ni = 0; ni < 4; ++ni) {
                float v = acc[mi][ni][reg];
                s += v * v;
            }
            s += __shfl_xor(s, 1); s += __shfl_xor(s, 2);
            s += __shfl_xor(s, 4); s += __shfl_xor(s, 8);
            ps[mi][reg] = s;
        }
    if (l15 == 0) {
#pragma unroll
        for (int mi = 0; mi < 4; ++mi)
#pragma unroll
            for (int reg = 0; reg < 4; ++reg)
                rssq[w][mi * 16 + quad * 4 + reg] = ps[mi][reg];
    }
    __syncthreads();
    if (tid < 64) {
        float ssq = rssq[0][tid] + rssq[1][tid] + rssq[2][tid] + rssq[3][tid];
        rinv[tid] = 1.69864360f / fmaxf(sqrtf(ssq), 1e-12f);
    }
    __syncthreads();

    const int r0  = arow0;                 // multiple of 64
    const int bb  = (r0 >> 12) & 3;
    const int l0  = r0 & 4095;
    unsigned char* dst = zn8 + ((size_t)(bb * 2 + set) * 4096 + l0) * 256;
    const int colbase = w * 64 + l15;
#pragma unroll
    for (int mi = 0; mi < 4; ++mi)
#pragma unroll
        for (int reg = 0; reg < 4; ++reg) {
            const int rl = mi * 16 + quad * 4 + reg;
            const float inv = rinv[rl];
#pragma unroll
            for (int ni = 0; ni < 4; ++ni)
                dst[(size_t)rl * 256 + colbase + ni * 16] =
                    f2fp8(acc[mi][ni][reg] * inv);
        }
}

// ---------------------------------------------------------------------------
// FP8 symmetric flash-gram (R16 exact, 67.3us measured): grid 512 x 256thr
// (4 waves, 2wm x 2wn).  Block = (batch, pair p, quarter); pair = row-
// stripes {p, 63-p}, 65 tiles, quarters 17/16/16/16.  Dbuf 2x32KB B staging
// (gl_lds16 prefetch overlaps MFMA+epilogue); A-frags (fp8 regs) reloaded
// at the row break.  Row-sums in regs -> atomic flush per stripe.  Col-sums
// (symmetry) per off-diag tile -> non-atomic store into plane
// Cc[batch][2*row+wm][8192].  Cross tiles (tj==row+32): d-dot extraction.
// setprio(1) wraps the MFMA cluster.  ONE barrier per tile.
// ---------------------------------------------------------------------------
#if defined(__has_builtin)
#if __has_builtin(__builtin_amdgcn_mfma_scale_f32_16x16x128_f8f6f4)
#define HAVE_MX 1
#endif
#endif

__global__ __launch_bounds__(256, 2) void gram_fp8_sym_kernel(
    const unsigned char* __restrict__ zn8, float* __restrict__ S,
    float* __restrict__ Cc, float* __restrict__ out)
{
    __shared__ unsigned char lsB[2][32768];   // [buf][kp 0..15][col 0..127][16B]

    const int bx    = blockIdx.x;             // 0..511
    const int xcd   = bx & 7;                 // batch -> XCD pair {2b,2b+1}
    const int batch = xcd >> 1;
    const int sub   = (bx >> 3) * 2 + (xcd & 1);   // 0..127
    const int p     = sub >> 2;               // pair 0..31
    const int qu    = sub & 3;                // quarter
    const int u0    = (qu == 0) ? 0 : 17 + (qu - 1) * 16;
    const int u1    = u0 + ((qu == 0) ? 17 : 16);
    const int ubrk  = 64 - p;                 // first tile index of row 63-p

    const unsigned char* Z = zn8 + (size_t)batch * 2097152;

    const int tid  = threadIdx.x;
    const int w    = tid >> 6;
    const int lane = tid & 63;
    const int wm   = w & 1;                   // 64-row band
    const int wn   = w >> 1;                  // 64-col band
    const int quad = lane >> 4;
    const int l15  = lane & 15;

#define TJ_OF(u)  ((u) < ubrk ? p + (u) : (u) - 1)
#define ROW_OF(u) ((u) < ubrk ? p : 63 - p)

#define STAGE_B(t, buf)                                                       \
    {                                                                         \
        const unsigned char* Bb = Z + (size_t)(t) * 128 * 256;                \
        _Pragma("unroll")                                                     \
        for (int r = 0; r < 8; ++r) {                                         \
            const int c   = w * 8 + r;                                        \
            const int u_  = c * 64 + lane;                                    \
            const int kp  = u_ >> 7;                                          \
            const int col = u_ & 127;                                         \
            gl_lds16(Bb + (size_t)col * 256 + kp * 16,                        \
                     &lsB[buf][(size_t)c * 1024]);                            \
        }                                                                     \
    }

    float rs[4][4];
#pragma unroll
    for (int mi = 0; mi < 4; ++mi)
#pragma unroll
        for (int reg = 0; reg < 4; ++reg)
            rs[mi][reg] = 0.f;
    float dsum = 0.f;

#define FLUSH_RS(rowstripe)                                                   \
    {                                                                         \
        float* Sr = S + (size_t)batch * 8192 + (rowstripe) * 128 + wm * 64;   \
        _Pragma("unroll")                                                     \
        for (int mi = 0; mi < 4; ++mi)                                        \
            _Pragma("unroll")                                                 \
            for (int reg = 0; reg < 4; ++reg) {                               \
                float v = rs[mi][reg];                                        \
                v += __shfl_xor(v, 1); v += __shfl_xor(v, 2);                 \
                v += __shfl_xor(v, 4); v += __shfl_xor(v, 8);                 \
                if (l15 == 0)                                                 \
                    atomicAdd(&Sr[mi * 16 + quad * 4 + reg], v);              \
                rs[mi][reg] = 0.f;                                            \
            }                                                                 \
    }

    int currow = ROW_OF(u0);

#ifdef HAVE_MX
    int8v afr[4][2];
#define LOAD_A(rowstripe)                                                     \
    {                                                                         \
        const unsigned char* Ab = Z + (size_t)((rowstripe) * 128 + wm * 64) * 256; \
        _Pragma("unroll")                                                     \
        for (int mi = 0; mi < 4; ++mi)                                        \
            _Pragma("unroll")                                                 \
            for (int ks = 0; ks < 2; ++ks) {                                  \
                const unsigned char* pA = Ab + (size_t)(mi * 16 + l15) * 256  \
                                          + ks * 128 + quad * 32;             \
                int4v lo = *(const int4v*)pA;                                 \
                int4v hi = *(const int4v*)(pA + 16);                          \
                afr[mi][ks] = __builtin_shufflevector(lo, hi, 0,1,2,3,4,5,6,7); \
            }                                                                 \
    }
#else
    long afr[4][8];
#define LOAD_A(rowstripe)                                                     \
    {                                                                         \
        const unsigned char* Ab = Z + (size_t)((rowstripe) * 128 + wm * 64) * 256; \
        _Pragma("unroll")                                                     \
        for (int mi = 0; mi < 4; ++mi)                                        \
            _Pragma("unroll")                                                 \
            for (int kc = 0; kc < 8; ++kc)                                    \
                afr[mi][kc] = *(const long*)(Ab + (size_t)(mi * 16 + l15) * 256 \
                                             + kc * 32 + quad * 8);           \
    }
#endif

    LOAD_A(currow);
    STAGE_B(TJ_OF(u0), 0);
    __syncthreads();

    for (int ui = u0; ui < u1; ++ui) {
        const int buf = (ui - u0) & 1;
        const int row = ROW_OF(ui);
        const int tj  = TJ_OF(ui);
        if (row != currow) {                  // crossed into row 63-p
            FLUSH_RS(currow);
            LOAD_A(row);
            currow = row;
        }
        if (ui + 1 < u1) STAGE_B(TJ_OF(ui + 1), buf ^ 1);

        float4v acc[4][4];
#pragma unroll
        for (int mi = 0; mi < 4; ++mi)
#pragma unroll
            for (int ni = 0; ni < 4; ++ni)
                acc[mi][ni] = (float4v){0.f, 0.f, 0.f, 0.f};

        const unsigned char* lb = &lsB[buf][0];
        __builtin_amdgcn_s_setprio(1);
#ifdef HAVE_MX
#pragma unroll
        for (int ks = 0; ks < 2; ++ks) {
            const int kp0 = ks * 8 + quad * 2;
            int8v bfv[4];
#pragma unroll
            for (int ni = 0; ni < 4; ++ni) {
                const unsigned char* pB = lb +
                    ((size_t)kp0 * 128 + wn * 64 + ni * 16 + l15) * 16;
                int4v lo = *(const int4v*)pB;
                int4v hi = *(const int4v*)(pB + 2048);   // kp0+1 slot
                bfv[ni] = __builtin_shufflevector(lo, hi, 0,1,2,3,4,5,6,7);
            }
#pragma unroll
            for (int mi = 0; mi < 4; ++mi)
#pragma unroll
                for (int ni = 0; ni < 4; ++ni)
                    acc[mi][ni] = __builtin_amdgcn_mfma_scale_f32_16x16x128_f8f6f4(
                        afr[mi][ks], bfv[ni], acc[mi][ni],
                        0, 0,                     // cbsz=E4M3, blgp=E4M3
                        0, 0x7F7F7F7F,            // scale A = 1.0
                        0, 0x7F7F7F7F);           // scale B = 1.0
        }
#else
#pragma unroll
        for (int kc = 0; kc < 8; ++kc) {
            const int kseg = kc * 4 + quad;
            const int kp   = kseg >> 1;
            const int hf   = kseg & 1;
            long bfv[4];
#pragma unroll
            for (int ni = 0; ni < 4; ++ni)
                bfv[ni] = *(const long*)(lb +
                    ((size_t)kp * 128 + wn * 64 + ni * 16 + l15) * 16 + hf * 8);
#pragma unroll
            for (int mi = 0; mi < 4; ++mi)
#pragma unroll
                for (int ni = 0; ni < 4; ++ni)
                    acc[mi][ni] = __builtin_amdgcn_mfma_f32_16x16x32_fp8_fp8(
                        afr[mi][kc], bfv[ni], acc[mi][ni], 0, 0, 0);
        }
#endif
        __builtin_amdgcn_s_setprio(0);

        // ---- cross tile: extract (q,q+4096) dots (raw acc, BEFORE exp)
        if (tj == row + 32) {
#pragma unroll
            for (int mi = 0; mi < 4; ++mi)
#pragma unroll
                for (int ni = 0; ni < 4; ++ni)
#pragma unroll
                    for (int reg = 0; reg < 4; ++reg) {
                        const int r = wm * 64 + mi * 16 + quad * 4 + reg;
                        const int c = wn * 64 + ni * 16 + l15;
                        if (r == c) dsum += acc[mi][ni][reg];
                    }
        }

        // ---- exp2 in place (acc already = 2*log2e*dot via zn8 scaling)
#pragma unroll
        for (int mi = 0; mi < 4; ++mi)
#pragma unroll
            for (int ni = 0; ni < 4; ++ni)
#pragma unroll
                for (int reg = 0; reg < 4; ++reg)
                    acc[mi][ni][reg] = EXP2F(acc[mi][ni][reg]);

        // ---- row sums accumulate in regs
#pragma unroll
        for (int mi = 0; mi < 4; ++mi)
#pragma unroll
            for (int reg = 0; reg < 4; ++reg)
                rs[mi][reg] += acc[mi][0][reg] + acc[mi][1][reg]
                             + acc[mi][2][reg] + acc[mi][3][reg];

        // ---- col sums (symmetry): per-wave 64-row partial -> own plane
        if (tj > row) {
            float* Cd = Cc + ((size_t)batch * 128 + row * 2 + wm) * 8192
                        + tj * 128 + wn * 64;
#pragma unroll
            for (int ni = 0; ni < 4; ++ni) {
                float s = 0.f;
#pragma unroll
                for (int mi = 0; mi < 4; ++mi)
#pragma unroll
                    for (int reg = 0; reg < 4; ++reg)
                        s += acc[mi][ni][reg];
                s += __shfl_xor(s, 16); s += __shfl_xor(s, 32);
                if (quad == 0)
                    Cd[ni * 16 + l15] = s;
            }
        }
        __syncthreads();                      // single per-tile barrier
    }

    FLUSH_RS(currow);

    // dv = 2*log2e * sum(d);  need -0.5*sum(d) -> factor -0.25*ln2
    {
        float dv = dsum;
        dv += __shfl_xor(dv, 1);  dv += __shfl_xor(dv, 2);
        dv += __shfl_xor(dv, 4);  dv += __shfl_xor(dv, 8);
        dv += __shfl_xor(dv, 16); dv += __shfl_xor(dv, 32);
        if (lane == 0 && dv != 0.f)
            atomicAdd(out, -0.17328680f * dv);
    }
#undef STAGE_B
#undef LOAD_A
#undef FLUSH_RS
#undef TJ_OF
#undef ROW_OF
}

// ---------------------------------------------------------------------------
// final: out += 0.125 * sum_{b,q} log(S[b][q] + sum_{r<2*(q>>7)} Cc[b][r][q] - e^2)
// grid 128 x 256 (one thread per (b,q)).  Only valid (written) planes read.
// ---------------------------------------------------------------------------
__global__ __launch_bounds__(256) void final_log_kernel(
    const float* __restrict__ S, const float* __restrict__ Cc,
    float* __restrict__ out)
{
    __shared__ float red[4];
    const int tid  = threadIdx.x;
    const int w    = tid >> 6;
    const int lane = tid & 63;
    const float E2 = 7.3890560989306495f;

    const int i = blockIdx.x * 256 + tid;     // 0..32767
    const int b = i >> 13;
    const int q = i & 8191;
    float s = S[i];
    const float* Cp = Cc + (size_t)b * 128 * 8192 + q;
    const int np = (q >> 7) * 2;              // planes 0..np-1 are written
    for (int r = 0; r < np; ++r)
        s += Cp[(size_t)r * 8192];
    float acc = logf(s - E2);

    acc += __shfl_xor(acc, 1);  acc += __shfl_xor(acc, 2);
    acc += __shfl_xor(acc, 4);  acc += __shfl_xor(acc, 8);
    acc += __shfl_xor(acc, 16); acc += __shfl_xor(acc, 32);
    if (lane == 0) red[w] = acc;
    __syncthreads();
    if (tid == 0)
        atomicAdd(out, 0.125f * (red[0] + red[1] + red[2] + red[3]));
}

// ---------------------------------------------------------------------------
// Workspace (bytes), total ~25.6 MB:
//   [0,       131072)  S (4*8192 fp32)
//   [131072,  262144)  W1bf
//   [262144,  393216)  W2bf
//   [393216,  8781824) zn8 (fp8, 8.39MB)
//   [8781824, 25559040) Cc (col-sum planes, 4*128*8192 fp32 = 16.78MB;
//                      no memset: final reads only written planes)
// ---------------------------------------------------------------------------
extern "C" void kernel_launch(void* const* d_in, const int* in_sizes, int n_in,
                              void* d_out, int out_size, void* d_ws, size_t ws_size,
                              hipStream_t stream)
{
    const float* X1 = (const float*)d_in[0];
    const float* X2 = (const float*)d_in[1];
    const float* W1 = (const float*)d_in[2];
    const float* b1 = (const float*)d_in[3];
    const float* W2 = (const float*)d_in[4];
    const float* b2 = (const float*)d_in[5];

    char* ws = (char*)d_ws;
    float* S    = (float*)(ws + 0);
    short* W1bf = (short*)(ws + 131072);
    short* W2bf = (short*)(ws + 262144);
    unsigned char* zn8 = (unsigned char*)(ws + 393216);
    float* Cc   = (float*)(ws + 8781824);

    convW_zero_kernel<<<128, 256, 0, stream>>>(W1, W2, W1bf, W2bf,
                                               S, (float*)d_out);
    fusedproj_kernel<<<512, 256, 0, stream>>>(X1, X2, W1bf, b1, W2bf, b2, zn8);
    gram_fp8_sym_kernel<<<512, 256, 0, stream>>>(zn8, S, Cc, (float*)d_out);
    final_log_kernel<<<128, 256, 0, stream>>>(S, Cc, (float*)d_out);
}

// Round 12
// 199.645 us; speedup vs baseline: 1.8426x; 1.0642x over previous
//
#include <hip/hip_runtime.h>
#include <math.h>

// ---------------------------------------------------------------------------
// Problem: B=4, L=4096, D=P=256, tau=0.5
// out = (1/8) * sum_{b,l} [ log(S1-e^2) + log(S2-e^2) - 4*d[b,l] ]
//   S[b,q] = sum_{m<2L} exp(2 * Zhat[b,q].Zhat[b,m]),  Zhat = [z1n; z2n]
// R23 = R21 + fusedproj X-staging fix.  R22 lesson: hipLaunchCooperative-
// Kernel silently no-ops under the harness graph capture (absmax == |ref|,
// kernel never ran) -> cooperative mega-kernel is off the table.
// R20 profile showed fusedproj at MfmaUtil 3.6%: phase-1 A-frags were
// fresh global fp32 X loads + cvt ON the MFMA critical path, re-read 4x
// over the kt loop.  Fix: stage the block's X tile (64x256 fp32 -> bf16,
// 32KB) into LDS ONCE (coalesced 1KB reads), unioned with lsH (X dead
// before H written; LDS total unchanged 66816B, 2 blocks/CU).  Phase-1
// A-reads become the proven phase-2 ds_read pattern.  gram/convW/final =
// R21 verbatim (gram 67.3us reproduced twice).
// ---------------------------------------------------------------------------

typedef __attribute__((ext_vector_type(8))) short short8;
typedef __attribute__((ext_vector_type(4))) short short4v;
typedef __attribute__((ext_vector_type(4))) float float4v;
typedef __attribute__((ext_vector_type(8))) int int8v;
typedef __attribute__((ext_vector_type(4))) int int4v;

#if defined(__has_builtin)
#if __has_builtin(__builtin_amdgcn_exp2f)
#define EXP2F(x) __builtin_amdgcn_exp2f(x)
#endif
#endif
#ifndef EXP2F
#define EXP2F(x) __expf(0.69314718056f * (x))
#endif

__device__ __forceinline__ short f2bf(float f) {
    unsigned u = __builtin_bit_cast(unsigned, f);
    u += 0x7fffu + ((u >> 16) & 1u);          // RNE
    return (short)(u >> 16);
}

// manual fp32 -> fp8 e4m3fn (OCP), RNE.  |f| <= ~1.7 here.
__device__ __forceinline__ unsigned char f2fp8(float f) {
    float af = fabsf(f);
    unsigned s = (__builtin_bit_cast(unsigned, f) >> 31) << 7;
    if (af < 0.015625f) {                     // subnormal (<2^-6); 8 rolls up
        int q = (int)rintf(af * 512.0f);
        return (unsigned char)(s | (unsigned)q);
    }
    unsigned au = __builtin_bit_cast(unsigned, af);
    au += 0x7FFFFu + ((au >> 20) & 1u);       // RNE at bit 20
    int e = (int)(au >> 23) - 127;
    unsigned m = (au >> 20) & 7u;
    return (unsigned char)(s | (unsigned)((e + 7) << 3) | m);
}

__device__ __forceinline__ void gl_lds16(const void* g, void* l) {
    __builtin_amdgcn_global_load_lds(
        (const __attribute__((address_space(1))) void*)g,
        (__attribute__((address_space(3))) void*)l, 16, 0, 0);
}

// ---------------------------------------------------------------------------
// convW + zero: W1/W2 fp32 -> bf16 and zero S + out.  grid 128 x 256.
// ---------------------------------------------------------------------------
__global__ __launch_bounds__(256) void convW_zero_kernel(
    const float* __restrict__ W1, const float* __restrict__ W2,
    short* __restrict__ d1, short* __restrict__ d2,
    float* __restrict__ S, float* __restrict__ out)
{
    int i = blockIdx.x * 256 + threadIdx.x;   // 0..32767
    const float* src = (i < 16384) ? W1 : W2;
    short* dst = (i < 16384) ? d1 : d2;
    int j = i & 16383;
    float4v v = ((const float4v*)src)[j];
    short4v o;
    o.x = f2bf(v.x); o.y = f2bf(v.y); o.z = f2bf(v.z); o.w = f2bf(v.w);
    ((short4v*)dst)[j] = o;
    S[i] = 0.f;
    if (i == 0) *out = 0.f;
}

// ---------------------------------------------------------------------------
// fused proj R23: per 64-row block:
//   stage: X tile (64x256 fp32) -> coalesced load + f2bf -> lsXH
//          [kc 0..31][row 0..63][8] (one-time; ds_write conflicts accepted)
//   phase1: acc = X*W1^T  (A-frags ds_read from lsXH; W1 staged in lsB)
//           -> +b1, elu -> bf16 -> lsXH (reused as lsH; X dead by then)
//   phase2: acc = H*W2^T (A-frags from lsXH, W2 staged per kt)
//   epilogue: +b2, rownorm -> zn8 = fp8(sqrt(2*log2e)*z/||z||)
// grid 512 x 256thr.  LDS 66816B -> 2 blocks/CU.
// ---------------------------------------------------------------------------
__global__ __launch_bounds__(256, 2) void fusedproj_kernel(
    const float* __restrict__ X1, const float* __restrict__ X2,
    const short* __restrict__ W1bf, const float* __restrict__ b1,
    const short* __restrict__ W2bf, const float* __restrict__ b2,
    unsigned char* __restrict__ zn8)
{
    __shared__ short lsB[16384];   // 32KB W1/W2 staging
    __shared__ short lsXH[16384];  // 32KB X (staged) then H (staged layout)
    __shared__ float rssq[4][64];
    __shared__ float rinv[64];

    const int arow0 = blockIdx.x * 64;
    const int tid  = threadIdx.x;
    const int w    = tid >> 6;
    const int lane = tid & 63;
    const int quad = lane >> 4;
    const int l15  = lane & 15;

    const int set = arow0 >> 14;
    const float* Xs = (set ? X2 : X1) + (size_t)(arow0 & 16383) * 256;

    // ---- stage X: 64 rows x 256 fp32, coalesced (32 consecutive kc per
    // quarter-wave = contiguous 1KB) -> bf16 lsXH[kc][row][8].
    // No barrier here: phase-1 kt=0's __syncthreads covers these ds_writes.
#pragma unroll
    for (int i = 0; i < 8; ++i) {
        const int oct = i * 256 + tid;        // 0..2047: row=oct>>5, kc=oct&31
        const int row = oct >> 5;
        const int kc  = oct & 31;
        const float* xp = Xs + (size_t)row * 256 + kc * 8;
        float4v a0 = *(const float4v*)xp;
        float4v a1 = *(const float4v*)(xp + 4);
        short8 t;
        t[0] = f2bf(a0.x); t[1] = f2bf(a0.y);
        t[2] = f2bf(a0.z); t[3] = f2bf(a0.w);
        t[4] = f2bf(a1.x); t[5] = f2bf(a1.y);
        t[6] = f2bf(a1.z); t[7] = f2bf(a1.w);
        *(short8*)(lsXH + (size_t)kc * 512 + row * 8) = t;
    }

    float4v acc[4][4];
#pragma unroll
    for (int mi = 0; mi < 4; ++mi)
#pragma unroll
        for (int ni = 0; ni < 4; ++ni)
            acc[mi][ni] = (float4v){0.f, 0.f, 0.f, 0.f};

    // ---- phase 1: X * W1^T  (A from lsXH, W1 staged per kt)
    for (int kt = 0; kt < 4; ++kt) {
        const int kbase = kt * 64;
#pragma unroll
        for (int r = 0; r < 8; ++r) {
            const int c   = w * 8 + r;        // 32 chunks of W1
            const int s   = c * 64 + lane;
            const int kc  = s >> 8;
            const int row = s & 255;
            gl_lds16(W1bf + (size_t)row * 256 + kbase + kc * 8,
                     lsB + (size_t)c * 512);
        }
        __syncthreads();                      // kt=0: also guards X staging
#pragma unroll
        for (int ks = 0; ks < 2; ++ks) {
            const int kc = ks * 4 + quad;
            short8 af[4], bfv[4];
#pragma unroll
            for (int mi = 0; mi < 4; ++mi)
                af[mi] = *(const short8*)(lsXH +
                    ((size_t)(kt * 8 + kc) * 64 + mi * 16 + l15) * 8);
#pragma unroll
            for (int ni = 0; ni < 4; ++ni)
                bfv[ni] = *(const short8*)(lsB +
                    ((size_t)kc * 256 + w * 64 + ni * 16 + l15) * 8);
#pragma unroll
            for (int mi = 0; mi < 4; ++mi)
#pragma unroll
                for (int ni = 0; ni < 4; ++ni)
                    acc[mi][ni] = __builtin_amdgcn_mfma_f32_16x16x32_bf16(
                        af[mi], bfv[ni], acc[mi][ni], 0, 0, 0);
        }
        __syncthreads();
    }

    // ---- epilogue 1: +b1, elu, bf16 -> lsXH (X dead; reuse as H)
    {
        const int rowbase = quad * 4;
        const int colbase = w * 64 + l15;
#pragma unroll
        for (int ni = 0; ni < 4; ++ni) {
            const int p  = colbase + ni * 16;
            const float bv = b1[p];
#pragma unroll
            for (int mi = 0; mi < 4; ++mi)
#pragma unroll
                for (int reg = 0; reg < 4; ++reg) {
                    const int row = rowbase + mi * 16 + reg;
                    float v = acc[mi][ni][reg] + bv;
                    v = (v > 0.f) ? v : expm1f(v);
                    lsXH[(size_t)(p >> 3) * 512 + row * 8 + (p & 7)] = f2bf(v);
                }
        }
    }

    // ---- phase 2: H * W2^T  (A from lsXH, B = W2 staged per kt)
#pragma unroll
    for (int mi = 0; mi < 4; ++mi)
#pragma unroll
        for (int ni = 0; ni < 4; ++ni)
            acc[mi][ni] = (float4v){0.f, 0.f, 0.f, 0.f};

    for (int kt = 0; kt < 4; ++kt) {
        const int kbase = kt * 64;
#pragma unroll
        for (int r = 0; r < 8; ++r) {
            const int c   = w * 8 + r;        // 0..31 chunks, all B
            const int s   = c * 64 + lane;
            const int kc  = s >> 8;
            const int row = s & 255;
            gl_lds16(W2bf + (size_t)row * 256 + kbase + kc * 8,
                     lsB + (size_t)c * 512);
        }
        __syncthreads();                      // kt=0: also guards lsH writes
#pragma unroll
        for (int ks = 0; ks < 2; ++ks) {
            const int kc = ks * 4 + quad;
            short8 af[4], bfv[4];
#pragma unroll
            for (int mi = 0; mi < 4; ++mi)
                af[mi] = *(const short8*)(lsXH +
                    ((size_t)(kt * 8 + kc) * 64 + mi * 16 + l15) * 8);
#pragma unroll
            for (int ni = 0; ni < 4; ++ni)
                bfv[ni] = *(const short8*)(lsB +
                    ((size_t)kc * 256 + w * 64 + ni * 16 + l15) * 8);
#pragma unroll
            for (int mi = 0; mi < 4; ++mi)
#pragma unroll
                for (int ni = 0; ni < 4; ++ni)
                    acc[mi][ni] = __builtin_amdgcn_mfma_f32_16x16x32_bf16(
                        af[mi], bfv[ni], acc[mi][ni], 0, 0, 0);
        }
        __syncthreads();
    }

    // ---- epilogue 2: +b2, normalize, fp8 out (sqrt(2*log2e) folded)
#pragma unroll
    for (int ni = 0; ni < 4; ++ni) {
        const float bv = b2[w * 64 + ni * 16 + l15];
#pragma unroll
        for (int mi = 0; mi < 4; ++mi)
#pragma unroll
            for (int reg = 0; reg < 4; ++reg)
                acc[mi][ni][reg] += bv;
    }
    float ps[4][4];
#pragma unroll
    for (int mi = 0; mi < 4; ++mi)
#pragma unroll
        for (int reg = 0; reg < 4; ++reg) {
            float s = 0.f;
#pragma unroll
            for (int ni = 0; ni < 4; ++ni) {
                float v = acc[mi][ni][reg];
                s += v * v;
            }
            s += __shfl_xor(s, 1); s += __shfl_xor(s, 2);
            s += __shfl_xor(s, 4); s += __shfl_xor(s, 8);
            ps[mi][reg] = s;
        }
    if (l15 == 0) {
#pragma unroll
        for (int mi = 0; mi < 4; ++mi)
#pragma unroll
            for (int reg = 0; reg < 4; ++reg)
                rssq[w][mi * 16 + quad * 4 + reg] = ps[mi][reg];
    }
    __syncthreads();
    if (tid < 64) {
        float ssq = rssq[0][tid] + rssq[1][tid] + rssq[2][tid] + rssq[3][tid];
        rinv[tid] = 1.69864360f / fmaxf(sqrtf(ssq), 1e-12f);
    }
    __syncthreads();

    const int r0  = arow0;                 // multiple of 64
    const int bb  = (r0 >> 12) & 3;
    const int l0  = r0 & 4095;
    unsigned char* dst = zn8 + ((size_t)(bb * 2 + set) * 4096 + l0) * 256;
    const int colbase = w * 64 + l15;
#pragma unroll
    for (int mi = 0; mi < 4; ++mi)
#pragma unroll
        for (int reg = 0; reg < 4; ++reg) {
            const int rl = mi * 16 + quad * 4 + reg;
            const float inv = rinv[rl];
#pragma unroll
            for (int ni = 0; ni < 4; ++ni)
                dst[(size_t)rl * 256 + colbase + ni * 16] =
                    f2fp8(acc[mi][ni][reg] * inv);
        }
}

// ---------------------------------------------------------------------------
// FP8 symmetric flash-gram (R16/R21 exact, 67.3us measured twice): grid
// 512 x 256thr (4 waves, 2wm x 2wn).  Block = (batch, pair p, quarter);
// pair = row-stripes {p, 63-p}, 65 tiles, quarters 17/16/16/16.  Dbuf
// 2x32KB B staging (gl_lds16 prefetch overlaps MFMA+epilogue); A-frags
// (fp8 regs) reloaded at the row break.  Row-sums in regs -> atomic flush
// per stripe.  Col-sums (symmetry) per off-diag tile -> non-atomic store
// into plane Cc[batch][2*row+wm][8192].  Cross tiles (tj==row+32): d-dot
// extraction.  setprio(1) wraps the MFMA cluster.  ONE barrier per tile.
// ---------------------------------------------------------------------------
#if defined(__has_builtin)
#if __has_builtin(__builtin_amdgcn_mfma_scale_f32_16x16x128_f8f6f4)
#define HAVE_MX 1
#endif
#endif

__global__ __launch_bounds__(256, 2) void gram_fp8_sym_kernel(
    const unsigned char* __restrict__ zn8, float* __restrict__ S,
    float* __restrict__ Cc, float* __restrict__ out)
{
    __shared__ unsigned char lsB[2][32768];   // [buf][kp 0..15][col 0..127][16B]

    const int bx    = blockIdx.x;             // 0..511
    const int xcd   = bx & 7;                 // batch -> XCD pair {2b,2b+1}
    const int batch = xcd >> 1;
    const int sub   = (bx >> 3) * 2 + (xcd & 1);   // 0..127
    const int p     = sub >> 2;               // pair 0..31
    const int qu    = sub & 3;                // quarter
    const int u0    = (qu == 0) ? 0 : 17 + (qu - 1) * 16;
    const int u1    = u0 + ((qu == 0) ? 17 : 16);
    const int ubrk  = 64 - p;                 // first tile index of row 63-p

    const unsigned char* Z = zn8 + (size_t)batch * 2097152;

    const int tid  = threadIdx.x;
    const int w    = tid >> 6;
    const int lane = tid & 63;
    const int wm   = w & 1;                   // 64-row band
    const int wn   = w >> 1;                  // 64-col band
    const int quad = lane >> 4;
    const int l15  = lane & 15;

#define TJ_OF(u)  ((u) < ubrk ? p + (u) : (u) - 1)
#define ROW_OF(u) ((u) < ubrk ? p : 63 - p)

#define STAGE_B(t, buf)                                                       \
    {                                                                         \
        const unsigned char* Bb = Z + (size_t)(t) * 128 * 256;                \
        _Pragma("unroll")                                                     \
        for (int r = 0; r < 8; ++r) {                                         \
            const int c   = w * 8 + r;                                        \
            const int u_  = c * 64 + lane;                                    \
            const int kp  = u_ >> 7;                                          \
            const int col = u_ & 127;                                         \
            gl_lds16(Bb + (size_t)col * 256 + kp * 16,                        \
                     &lsB[buf][(size_t)c * 1024]);                            \
        }                                                                     \
    }

    float rs[4][4];
#pragma unroll
    for (int mi = 0; mi < 4; ++mi)
#pragma unroll
        for (int reg = 0; reg < 4; ++reg)
            rs[mi][reg] = 0.f;
    float dsum = 0.f;

#define FLUSH_RS(rowstripe)                                                   \
    {                                                                         \
        float* Sr = S + (size_t)batch * 8192 + (rowstripe) * 128 + wm * 64;   \
        _Pragma("unroll")                                                     \
        for (int mi = 0; mi < 4; ++mi)                                        \
            _Pragma("unroll")                                                 \
            for (int reg = 0; reg < 4; ++reg) {                               \
                float v = rs[mi][reg];                                        \
                v += __shfl_xor(v, 1); v += __shfl_xor(v, 2);                 \
                v += __shfl_xor(v, 4); v += __shfl_xor(v, 8);                 \
                if (l15 == 0)                                                 \
                    atomicAdd(&Sr[mi * 16 + quad * 4 + reg], v);              \
                rs[mi][reg] = 0.f;                                            \
            }                                                                 \
    }

    int currow = ROW_OF(u0);

#ifdef HAVE_MX
    int8v afr[4][2];
#define LOAD_A(rowstripe)                                                     \
    {                                                                         \
        const unsigned char* Ab = Z + (size_t)((rowstripe) * 128 + wm * 64) * 256; \
        _Pragma("unroll")                                                     \
        for (int mi = 0; mi < 4; ++mi)                                        \
            _Pragma("unroll")                                                 \
            for (int ks = 0; ks < 2; ++ks) {                                  \
                const unsigned char* pA = Ab + (size_t)(mi * 16 + l15) * 256  \
                                          + ks * 128 + quad * 32;             \
                int4v lo = *(const int4v*)pA;                                 \
                int4v hi = *(const int4v*)(pA + 16);                          \
                afr[mi][ks] = __builtin_shufflevector(lo, hi, 0,1,2,3,4,5,6,7); \
            }                                                                 \
    }
#else
    long afr[4][8];
#define LOAD_A(rowstripe)                                                     \
    {                                                                         \
        const unsigned char* Ab = Z + (size_t)((rowstripe) * 128 + wm * 64) * 256; \
        _Pragma("unroll")                                                     \
        for (int mi = 0; mi < 4; ++mi)                                        \
            _Pragma("unroll")                                                 \
            for (int kc = 0; kc < 8; ++kc)                                    \
                afr[mi][kc] = *(const long*)(Ab + (size_t)(mi * 16 + l15) * 256 \
                                             + kc * 32 + quad * 8);           \
    }
#endif

    LOAD_A(currow);
    STAGE_B(TJ_OF(u0), 0);
    __syncthreads();

    for (int ui = u0; ui < u1; ++ui) {
        const int buf = (ui - u0) & 1;
        const int row = ROW_OF(ui);
        const int tj  = TJ_OF(ui);
        if (row != currow) {                  // crossed into row 63-p
            FLUSH_RS(currow);
            LOAD_A(row);
            currow = row;
        }
        if (ui + 1 < u1) STAGE_B(TJ_OF(ui + 1), buf ^ 1);

        float4v acc[4][4];
#pragma unroll
        for (int mi = 0; mi < 4; ++mi)
#pragma unroll
            for (int ni = 0; ni < 4; ++ni)
                acc[mi][ni] = (float4v){0.f, 0.f, 0.f, 0.f};

        const unsigned char* lb = &lsB[buf][0];
        __builtin_amdgcn_s_setprio(1);
#ifdef HAVE_MX
#pragma unroll
        for (int ks = 0; ks < 2; ++ks) {
            const int kp0 = ks * 8 + quad * 2;
            int8v bfv[4];
#pragma unroll
            for (int ni = 0; ni < 4; ++ni) {
                const unsigned char* pB = lb +
                    ((size_t)kp0 * 128 + wn * 64 + ni * 16 + l15) * 16;
                int4v lo = *(const int4v*)pB;
                int4v hi = *(const int4v*)(pB + 2048);   // kp0+1 slot
                bfv[ni] = __builtin_shufflevector(lo, hi, 0,1,2,3,4,5,6,7);
            }
#pragma unroll
            for (int mi = 0; mi < 4; ++mi)
#pragma unroll
                for (int ni = 0; ni < 4; ++ni)
                    acc[mi][ni] = __builtin_amdgcn_mfma_scale_f32_16x16x128_f8f6f4(
                        afr[mi][ks], bfv[ni], acc[mi][ni],
                        0, 0,                     // cbsz=E4M3, blgp=E4M3
                        0, 0x7F7F7F7F,            // scale A = 1.0
                        0, 0x7F7F7F7F);           // scale B = 1.0
        }
#else
#pragma unroll
        for (int kc = 0; kc < 8; ++kc) {
            const int kseg = kc * 4 + quad;
            const int kp   = kseg >> 1;
            const int hf   = kseg & 1;
            long bfv[4];
#pragma unroll
            for (int ni = 0; ni < 4; ++ni)
                bfv[ni] = *(const long*)(lb +
                    ((size_t)kp * 128 + wn * 64 + ni * 16 + l15) * 16 + hf * 8);
#pragma unroll
            for (int mi = 0; mi < 4; ++mi)
#pragma unroll
                for (int ni = 0; ni < 4; ++ni)
                    acc[mi][ni] = __builtin_amdgcn_mfma_f32_16x16x32_fp8_fp8(
                        afr[mi][kc], bfv[ni], acc[mi][ni], 0, 0, 0);
        }
#endif
        __builtin_amdgcn_s_setprio(0);

        // ---- cross tile: extract (q,q+4096) dots (raw acc, BEFORE exp)
        if (tj == row + 32) {
#pragma unroll
            for (int mi = 0; mi < 4; ++mi)
#pragma unroll
                for (int ni = 0; ni < 4; ++ni)
#pragma unroll
                    for (int reg = 0; reg < 4; ++reg) {
                        const int r = wm * 64 + mi * 16 + quad * 4 + reg;
                        const int c = wn * 64 + ni * 16 + l15;
                        if (r == c) dsum += acc[mi][ni][reg];
                    }
        }

        // ---- exp2 in place (acc already = 2*log2e*dot via zn8 scaling)
#pragma unroll
        for (int mi = 0; mi < 4; ++mi)
#pragma unroll
            for (int ni = 0; ni < 4; ++ni)
#pragma unroll
                for (int reg = 0; reg < 4; ++reg)
                    acc[mi][ni][reg] = EXP2F(acc[mi][ni][reg]);

        // ---- row sums accumulate in regs
#pragma unroll
        for (int mi = 0; mi < 4; ++mi)
#pragma unroll
            for (int reg = 0; reg < 4; ++reg)
                rs[mi][reg] += acc[mi][0][reg] + acc[mi][1][reg]
                             + acc[mi][2][reg] + acc[mi][3][reg];

        // ---- col sums (symmetry): per-wave 64-row partial -> own plane
        if (tj > row) {
            float* Cd = Cc + ((size_t)batch * 128 + row * 2 + wm) * 8192
                        + tj * 128 + wn * 64;
#pragma unroll
            for (int ni = 0; ni < 4; ++ni) {
                float s = 0.f;
#pragma unroll
                for (int mi = 0; mi < 4; ++mi)
#pragma unroll
                    for (int reg = 0; reg < 4; ++reg)
                        s += acc[mi][ni][reg];
                s += __shfl_xor(s, 16); s += __shfl_xor(s, 32);
                if (quad == 0)
                    Cd[ni * 16 + l15] = s;
            }
        }
        __syncthreads();                      // single per-tile barrier
    }

    FLUSH_RS(currow);

    // dv = 2*log2e * sum(d);  need -0.5*sum(d) -> factor -0.25*ln2
    {
        float dv = dsum;
        dv += __shfl_xor(dv, 1);  dv += __shfl_xor(dv, 2);
        dv += __shfl_xor(dv, 4);  dv += __shfl_xor(dv, 8);
        dv += __shfl_xor(dv, 16); dv += __shfl_xor(dv, 32);
        if (lane == 0 && dv != 0.f)
            atomicAdd(out, -0.17328680f * dv);
    }
#undef STAGE_B
#undef LOAD_A
#undef FLUSH_RS
#undef TJ_OF
#undef ROW_OF
}

// ---------------------------------------------------------------------------
// final: out += 0.125 * sum_{b,q} log(S[b][q] + sum_{r<2*(q>>7)} Cc[b][r][q] - e^2)
// grid 128 x 256 (one thread per (b,q)).  Only valid (written) planes read.
// ---------------------------------------------------------------------------
__global__ __launch_bounds__(256) void final_log_kernel(
    const float* __restrict__ S, const float* __restrict__ Cc,
    float* __restrict__ out)
{
    __shared__ float red[4];
    const int tid  = threadIdx.x;
    const int w    = tid >> 6;
    const int lane = tid & 63;
    const float E2 = 7.3890560989306495f;

    const int i = blockIdx.x * 256 + tid;     // 0..32767
    const int b = i >> 13;
    const int q = i & 8191;
    float s = S[i];
    const float* Cp = Cc + (size_t)b * 128 * 8192 + q;
    const int np = (q >> 7) * 2;              // planes 0..np-1 are written
    for (int r = 0; r < np; ++r)
        s += Cp[(size_t)r * 8192];
    float acc = logf(s - E2);

    acc += __shfl_xor(acc, 1);  acc += __shfl_xor(acc, 2);
    acc += __shfl_xor(acc, 4);  acc += __shfl_xor(acc, 8);
    acc += __shfl_xor(acc, 16); acc += __shfl_xor(acc, 32);
    if (lane == 0) red[w] = acc;
    __syncthreads();
    if (tid == 0)
        atomicAdd(out, 0.125f * (red[0] + red[1] + red[2] + red[3]));
}

// ---------------------------------------------------------------------------
// Workspace (bytes), total ~25.6 MB:
//   [0,       131072)  S (4*8192 fp32)
//   [131072,  262144)  W1bf
//   [262144,  393216)  W2bf
//   [393216,  8781824) zn8 (fp8, 8.39MB)
//   [8781824, 25559040) Cc (col-sum planes, 4*128*8192 fp32 = 16.78MB;
//                      no memset: final reads only written planes)
// ---------------------------------------------------------------------------
extern "C" void kernel_launch(void* const* d_in, const int* in_sizes, int n_in,
                              void* d_out, int out_size, void* d_ws, size_t ws_size,
                              hipStream_t stream)
{
    const float* X1 = (const float*)d_in[0];
    const float* X2 = (const float*)d_in[1];
    const float* W1 = (const float*)d_in[2];
    const float* b1 = (const float*)d_in[3];
    const float* W2 = (const float*)d_in[4];
    const float* b2 = (const float*)d_in[5];

    char* ws = (char*)d_ws;
    float* S    = (float*)(ws + 0);
    short* W1bf = (short*)(ws + 131072);
    short* W2bf = (short*)(ws + 262144);
    unsigned char* zn8 = (unsigned char*)(ws + 393216);
    float* Cc   = (float*)(ws + 8781824);

    convW_zero_kernel<<<128, 256, 0, stream>>>(W1, W2, W1bf, W2bf,
                                               S, (float*)d_out);
    fusedproj_kernel<<<512, 256, 0, stream>>>(X1, X2, W1bf, b1, W2bf, b2, zn8);
    gram_fp8_sym_kernel<<<512, 256, 0, stream>>>(zn8, S, Cc, (float*)d_out);
    final_log_kernel<<<128, 256, 0, stream>>>(S, Cc, (float*)d_out);
}

// Round 13
// 197.954 us; speedup vs baseline: 1.8583x; 1.0085x over previous
//
#include <hip/hip_runtime.h>
#include <math.h>

// ---------------------------------------------------------------------------
// Problem: B=4, L=4096, D=P=256, tau=0.5
// out = (1/8) * sum_{b,l} [ log(S1-e^2) + log(S2-e^2) - 4*d[b,l] ]
//   S[b,q] = sum_{m<2L} exp(2 * Zhat[b,q].Zhat[b,m]),  Zhat = [z1n; z2n]
// R24 = R23 + fusedproj restructured to gram's proven dbuf rhythm.
// R23 postmortem: fusedproj stuck at ~81us / MfmaUtil 3.9% because each
// kt was stage -> full vmcnt(0) barrier drain -> compute (no overlap);
// gram does stage(next) || compute(cur) -> ONE barrier and runs 67us at
// 2x the MFMA.  Changes (fusedproj only; gram/convW/final verbatim):
//  - BK 64->32: W staging dbuf 2x16KB (LDS 66.8KB, 2 blocks/CU kept).
//    16 uniform steps (8 per phase): STAGE_W(next slice, buf^1) ->
//    compute 16 MFMAs from buf -> one __syncthreads.  Phase2 slice 0
//    staged at s=7 (parity lands on lsB[0]).
//  - lsXH XOR swizzle (idx ^= (kc&7)<<3 shorts) on all 4 access sites:
//    kills the 32-way staging ds_write bank conflict (1.18M cycles).
// ---------------------------------------------------------------------------

typedef __attribute__((ext_vector_type(8))) short short8;
typedef __attribute__((ext_vector_type(4))) short short4v;
typedef __attribute__((ext_vector_type(4))) float float4v;
typedef __attribute__((ext_vector_type(8))) int int8v;
typedef __attribute__((ext_vector_type(4))) int int4v;

#if defined(__has_builtin)
#if __has_builtin(__builtin_amdgcn_exp2f)
#define EXP2F(x) __builtin_amdgcn_exp2f(x)
#endif
#endif
#ifndef EXP2F
#define EXP2F(x) __expf(0.69314718056f * (x))
#endif

__device__ __forceinline__ short f2bf(float f) {
    unsigned u = __builtin_bit_cast(unsigned, f);
    u += 0x7fffu + ((u >> 16) & 1u);          // RNE
    return (short)(u >> 16);
}

// manual fp32 -> fp8 e4m3fn (OCP), RNE.  |f| <= ~1.7 here.
__device__ __forceinline__ unsigned char f2fp8(float f) {
    float af = fabsf(f);
    unsigned s = (__builtin_bit_cast(unsigned, f) >> 31) << 7;
    if (af < 0.015625f) {                     // subnormal (<2^-6); 8 rolls up
        int q = (int)rintf(af * 512.0f);
        return (unsigned char)(s | (unsigned)q);
    }
    unsigned au = __builtin_bit_cast(unsigned, af);
    au += 0x7FFFFu + ((au >> 20) & 1u);       // RNE at bit 20
    int e = (int)(au >> 23) - 127;
    unsigned m = (au >> 20) & 7u;
    return (unsigned char)(s | (unsigned)((e + 7) << 3) | m);
}

__device__ __forceinline__ void gl_lds16(const void* g, void* l) {
    __builtin_amdgcn_global_load_lds(
        (const __attribute__((address_space(1))) void*)g,
        (__attribute__((address_space(3))) void*)l, 16, 0, 0);
}

// lsXH swizzled index (in shorts) of the 8-short group (kc 0..31, row 0..63).
// XOR of (kc&7)<<3 flips row bits 0..2 -> staging write spreads 32 lanes
// over 8 banks instead of 1.  Bijective; groups of 8 shorts stay intact.
__device__ __forceinline__ int xh_idx(int kc, int row) {
    return (((kc << 6) | row) << 3) ^ ((kc & 7) << 3);
}

// ---------------------------------------------------------------------------
// convW + zero: W1/W2 fp32 -> bf16 and zero S + out.  grid 128 x 256.
// ---------------------------------------------------------------------------
__global__ __launch_bounds__(256) void convW_zero_kernel(
    const float* __restrict__ W1, const float* __restrict__ W2,
    short* __restrict__ d1, short* __restrict__ d2,
    float* __restrict__ S, float* __restrict__ out)
{
    int i = blockIdx.x * 256 + threadIdx.x;   // 0..32767
    const float* src = (i < 16384) ? W1 : W2;
    short* dst = (i < 16384) ? d1 : d2;
    int j = i & 16383;
    float4v v = ((const float4v*)src)[j];
    short4v o;
    o.x = f2bf(v.x); o.y = f2bf(v.y); o.z = f2bf(v.z); o.w = f2bf(v.w);
    ((short4v*)dst)[j] = o;
    S[i] = 0.f;
    if (i == 0) *out = 0.f;
}

// ---------------------------------------------------------------------------
// fused proj R24: per 64-row block, 4 waves x 64 cols.
//   prologue: stage X tile (64x256 fp32 -> bf16) -> swizzled lsXH;
//             stage W1 slice 0 (16KB) -> lsB[0]; barrier.
//   16 steps (8 phase1 + 8 phase2), each: STAGE_W(next, buf^1) ->
//     16 MFMA (K=32, af from lsXH octet s*4+quad, bfv from lsB[buf]) ->
//     one barrier.  Phase2 slice 0 staged at s=7.
//   epilogue1 (between phases): +b1, elu -> bf16 -> lsXH (X dead), barrier.
//   epilogue2: +b2, rownorm -> zn8 = fp8(sqrt(2*log2e)*z/||z||).
// grid 512 x 256thr.  LDS 66816B -> 2 blocks/CU.
// ---------------------------------------------------------------------------
__global__ __launch_bounds__(256, 2) void fusedproj_kernel(
    const float* __restrict__ X1, const float* __restrict__ X2,
    const short* __restrict__ W1bf, const float* __restrict__ b1,
    const short* __restrict__ W2bf, const float* __restrict__ b2,
    unsigned char* __restrict__ zn8)
{
    __shared__ short lsB[2][8192];   // 2 x 16KB: [kc 0..3][256 rows][8]
    __shared__ short lsXH[16384];    // 32KB X (staged,swz) then H (swz)
    __shared__ float rssq[4][64];
    __shared__ float rinv[64];

    const int arow0 = blockIdx.x * 64;
    const int tid  = threadIdx.x;
    const int w    = tid >> 6;
    const int lane = tid & 63;
    const int quad = lane >> 4;
    const int l15  = lane & 15;

    const int set = arow0 >> 14;
    const float* Xs = (set ? X2 : X1) + (size_t)(arow0 & 16383) * 256;

// stage one 16KB W slice (256 rows x 32 k bf16) into lsB[bufp].
// chunk c = w*4+r (0..15): sidx = c*64+lane -> kc = sidx>>8, row = sidx&255.
#define STAGE_W(Wsrc, slice, bufp)                                            \
    {                                                                         \
        _Pragma("unroll")                                                     \
        for (int r = 0; r < 4; ++r) {                                         \
            const int c    = w * 4 + r;                                       \
            const int sidx = c * 64 + lane;                                   \
            const int kc   = sidx >> 8;                                       \
            const int row  = sidx & 255;                                      \
            gl_lds16((Wsrc) + (size_t)row * 256 + (slice) * 32 + kc * 8,      \
                     &lsB[bufp][(size_t)c * 512]);                            \
        }                                                                     \
    }

    // ---- prologue: stage W1 slice 0 (async) + X tile -> lsXH (swizzled)
    STAGE_W(W1bf, 0, 0);
#pragma unroll
    for (int i = 0; i < 8; ++i) {
        const int oct = i * 256 + tid;        // row = oct>>5, kc = oct&31
        const int row = oct >> 5;
        const int kc  = oct & 31;
        const float* xp = Xs + (size_t)row * 256 + kc * 8;
        float4v a0 = *(const float4v*)xp;
        float4v a1 = *(const float4v*)(xp + 4);
        short8 t;
        t[0] = f2bf(a0.x); t[1] = f2bf(a0.y);
        t[2] = f2bf(a0.z); t[3] = f2bf(a0.w);
        t[4] = f2bf(a1.x); t[5] = f2bf(a1.y);
        t[6] = f2bf(a1.z); t[7] = f2bf(a1.w);
        *(short8*)(lsXH + xh_idx(kc, row)) = t;
    }
    __syncthreads();

    float4v acc[4][4];
#pragma unroll
    for (int mi = 0; mi < 4; ++mi)
#pragma unroll
        for (int ni = 0; ni < 4; ++ni)
            acc[mi][ni] = (float4v){0.f, 0.f, 0.f, 0.f};

    // ---- phase 1: X * W1^T, 8 steps of K=32, dbuf prefetch
    for (int s = 0; s < 8; ++s) {
        if (s < 7) STAGE_W(W1bf, s + 1, (s + 1) & 1)
        else       STAGE_W(W2bf, 0, 0)            // (7+1)&1 == 0
        const short* lb = lsB[s & 1];
        short8 af[4], bfv[4];
#pragma unroll
        for (int mi = 0; mi < 4; ++mi)
            af[mi] = *(const short8*)(lsXH + xh_idx(s * 4 + quad, mi * 16 + l15));
#pragma unroll
        for (int ni = 0; ni < 4; ++ni)
            bfv[ni] = *(const short8*)(lb +
                (size_t)quad * 2048 + ((size_t)w * 64 + ni * 16 + l15) * 8);
        __builtin_amdgcn_s_setprio(1);
#pragma unroll
        for (int mi = 0; mi < 4; ++mi)
#pragma unroll
            for (int ni = 0; ni < 4; ++ni)
                acc[mi][ni] = __builtin_amdgcn_mfma_f32_16x16x32_bf16(
                    af[mi], bfv[ni], acc[mi][ni], 0, 0, 0);
        __builtin_amdgcn_s_setprio(0);
        __syncthreads();
    }

    // ---- epilogue 1: +b1, elu, bf16 -> lsXH (X dead; reuse as H, swz)
    {
        const int rowbase = quad * 4;
        const int colbase = w * 64 + l15;
#pragma unroll
        for (int ni = 0; ni < 4; ++ni) {
            const int p  = colbase + ni * 16;
            const float bv = b1[p];
#pragma unroll
            for (int mi = 0; mi < 4; ++mi)
#pragma unroll
                for (int reg = 0; reg < 4; ++reg) {
                    const int row = rowbase + mi * 16 + reg;
                    float v = acc[mi][ni][reg] + bv;
                    v = (v > 0.f) ? v : expm1f(v);
                    lsXH[xh_idx(p >> 3, row) + (p & 7)] = f2bf(v);
                }
        }
    }
    __syncthreads();                              // H visible to all waves

#pragma unroll
    for (int mi = 0; mi < 4; ++mi)
#pragma unroll
        for (int ni = 0; ni < 4; ++ni)
            acc[mi][ni] = (float4v){0.f, 0.f, 0.f, 0.f};

    // ---- phase 2: H * W2^T, 8 steps of K=32, dbuf prefetch
    for (int t = 0; t < 8; ++t) {
        if (t < 7) STAGE_W(W2bf, t + 1, (t + 1) & 1)
        const short* lb = lsB[t & 1];
        short8 af[4], bfv[4];
#pragma unroll
        for (int mi = 0; mi < 4; ++mi)
            af[mi] = *(const short8*)(lsXH + xh_idx(t * 4 + quad, mi * 16 + l15));
#pragma unroll
        for (int ni = 0; ni < 4; ++ni)
            bfv[ni] = *(const short8*)(lb +
                (size_t)quad * 2048 + ((size_t)w * 64 + ni * 16 + l15) * 8);
        __builtin_amdgcn_s_setprio(1);
#pragma unroll
        for (int mi = 0; mi < 4; ++mi)
#pragma unroll
            for (int ni = 0; ni < 4; ++ni)
                acc[mi][ni] = __builtin_amdgcn_mfma_f32_16x16x32_bf16(
                    af[mi], bfv[ni], acc[mi][ni], 0, 0, 0);
        __builtin_amdgcn_s_setprio(0);
        __syncthreads();
    }
#undef STAGE_W

    // ---- epilogue 2: +b2, normalize, fp8 out (sqrt(2*log2e) folded)
#pragma unroll
    for (int ni = 0; ni < 4; ++ni) {
        const float bv = b2[w * 64 + ni * 16 + l15];
#pragma unroll
        for (int mi = 0; mi < 4; ++mi)
#pragma unroll
            for (int reg = 0; reg < 4; ++reg)
                acc[mi][ni][reg] += bv;
    }
    float ps[4][4];
#pragma unroll
    for (int mi = 0; mi < 4; ++mi)
#pragma unroll
        for (int reg = 0; reg < 4; ++reg) {
            float s = 0.f;
#pragma unroll
            for (int ni = 0; ni < 4; ++ni) {
                float v = acc[mi][ni][reg];
                s += v * v;
            }
            s += __shfl_xor(s, 1); s += __shfl_xor(s, 2);
            s += __shfl_xor(s, 4); s += __shfl_xor(s, 8);
            ps[mi][reg] = s;
        }
    if (l15 == 0) {
#pragma unroll
        for (int mi = 0; mi < 4; ++mi)
#pragma unroll
            for (int reg = 0; reg < 4; ++reg)
                rssq[w][mi * 16 + quad * 4 + reg] = ps[mi][reg];
    }
    __syncthreads();
    if (tid < 64) {
        float ssq = rssq[0][tid] + rssq[1][tid] + rssq[2][tid] + rssq[3][tid];
        rinv[tid] = 1.69864360f / fmaxf(sqrtf(ssq), 1e-12f);
    }
    __syncthreads();

    const int bb  = (arow0 >> 12) & 3;
    const int l0  = arow0 & 4095;
    unsigned char* dst = zn8 + ((size_t)(bb * 2 + set) * 4096 + l0) * 256;
    const int colbase = w * 64 + l15;
#pragma unroll
    for (int mi = 0; mi < 4; ++mi)
#pragma unroll
        for (int reg = 0; reg < 4; ++reg) {
            const int rl = mi * 16 + quad * 4 + reg;
            const float inv = rinv[rl];
#pragma unroll
            for (int ni = 0; ni < 4; ++ni)
                dst[(size_t)rl * 256 + colbase + ni * 16] =
                    f2fp8(acc[mi][ni][reg] * inv);
        }
}

// ---------------------------------------------------------------------------
// FP8 symmetric flash-gram (R16/R21 exact, 67.3us measured 3x): grid
// 512 x 256thr (4 waves, 2wm x 2wn).  Block = (batch, pair p, quarter);
// pair = row-stripes {p, 63-p}, 65 tiles, quarters 17/16/16/16.  Dbuf
// 2x32KB B staging (gl_lds16 prefetch overlaps MFMA+epilogue); A-frags
// (fp8 regs) reloaded at the row break.  Row-sums in regs -> atomic flush
// per stripe.  Col-sums (symmetry) per off-diag tile -> non-atomic store
// into plane Cc[batch][2*row+wm][8192].  Cross tiles (tj==row+32): d-dot
// extraction.  setprio(1) wraps the MFMA cluster.  ONE barrier per tile.
// ---------------------------------------------------------------------------
#if defined(__has_builtin)
#if __has_builtin(__builtin_amdgcn_mfma_scale_f32_16x16x128_f8f6f4)
#define HAVE_MX 1
#endif
#endif

__global__ __launch_bounds__(256, 2) void gram_fp8_sym_kernel(
    const unsigned char* __restrict__ zn8, float* __restrict__ S,
    float* __restrict__ Cc, float* __restrict__ out)
{
    __shared__ unsigned char lsB[2][32768];   // [buf][kp 0..15][col 0..127][16B]

    const int bx    = blockIdx.x;             // 0..511
    const int xcd   = bx & 7;                 // batch -> XCD pair {2b,2b+1}
    const int batch = xcd >> 1;
    const int sub   = (bx >> 3) * 2 + (xcd & 1);   // 0..127
    const int p     = sub >> 2;               // pair 0..31
    const int qu    = sub & 3;                // quarter
    const int u0    = (qu == 0) ? 0 : 17 + (qu - 1) * 16;
    const int u1    = u0 + ((qu == 0) ? 17 : 16);
    const int ubrk  = 64 - p;                 // first tile index of row 63-p

    const unsigned char* Z = zn8 + (size_t)batch * 2097152;

    const int tid  = threadIdx.x;
    const int w    = tid >> 6;
    const int lane = tid & 63;
    const int wm   = w & 1;                   // 64-row band
    const int wn   = w >> 1;                  // 64-col band
    const int quad = lane >> 4;
    const int l15  = lane & 15;

#define TJ_OF(u)  ((u) < ubrk ? p + (u) : (u) - 1)
#define ROW_OF(u) ((u) < ubrk ? p : 63 - p)

#define STAGE_B(t, buf)                                                       \
    {                                                                         \
        const unsigned char* Bb = Z + (size_t)(t) * 128 * 256;                \
        _Pragma("unroll")                                                     \
        for (int r = 0; r < 8; ++r) {                                         \
            const int c   = w * 8 + r;                                        \
            const int u_  = c * 64 + lane;                                    \
            const int kp  = u_ >> 7;                                          \
            const int col = u_ & 127;                                         \
            gl_lds16(Bb + (size_t)col * 256 + kp * 16,                        \
                     &lsB[buf][(size_t)c * 1024]);                            \
        }                                                                     \
    }

    float rs[4][4];
#pragma unroll
    for (int mi = 0; mi < 4; ++mi)
#pragma unroll
        for (int reg = 0; reg < 4; ++reg)
            rs[mi][reg] = 0.f;
    float dsum = 0.f;

#define FLUSH_RS(rowstripe)                                                   \
    {                                                                         \
        float* Sr = S + (size_t)batch * 8192 + (rowstripe) * 128 + wm * 64;   \
        _Pragma("unroll")                                                     \
        for (int mi = 0; mi < 4; ++mi)                                        \
            _Pragma("unroll")                                                 \
            for (int reg = 0; reg < 4; ++reg) {                               \
                float v = rs[mi][reg];                                        \
                v += __shfl_xor(v, 1); v += __shfl_xor(v, 2);                 \
                v += __shfl_xor(v, 4); v += __shfl_xor(v, 8);                 \
                if (l15 == 0)                                                 \
                    atomicAdd(&Sr[mi * 16 + quad * 4 + reg], v);              \
                rs[mi][reg] = 0.f;                                            \
            }                                                                 \
    }

    int currow = ROW_OF(u0);

#ifdef HAVE_MX
    int8v afr[4][2];
#define LOAD_A(rowstripe)                                                     \
    {                                                                         \
        const unsigned char* Ab = Z + (size_t)((rowstripe) * 128 + wm * 64) * 256; \
        _Pragma("unroll")                                                     \
        for (int mi = 0; mi < 4; ++mi)                                        \
            _Pragma("unroll")                                                 \
            for (int ks = 0; ks < 2; ++ks) {                                  \
                const unsigned char* pA = Ab + (size_t)(mi * 16 + l15) * 256  \
                                          + ks * 128 + quad * 32;             \
                int4v lo = *(const int4v*)pA;                                 \
                int4v hi = *(const int4v*)(pA + 16);                          \
                afr[mi][ks] = __builtin_shufflevector(lo, hi, 0,1,2,3,4,5,6,7); \
            }                                                                 \
    }
#else
    long afr[4][8];
#define LOAD_A(rowstripe)                                                     \
    {                                                                         \
        const unsigned char* Ab = Z + (size_t)((rowstripe) * 128 + wm * 64) * 256; \
        _Pragma("unroll")                                                     \
        for (int mi = 0; mi < 4; ++mi)                                        \
            _Pragma("unroll")                                                 \
            for (int kc = 0; kc < 8; ++kc)                                    \
                afr[mi][kc] = *(const long*)(Ab + (size_t)(mi * 16 + l15) * 256 \
                                             + kc * 32 + quad * 8);           \
    }
#endif

    LOAD_A(currow);
    STAGE_B(TJ_OF(u0), 0);
    __syncthreads();

    for (int ui = u0; ui < u1; ++ui) {
        const int buf = (ui - u0) & 1;
        const int row = ROW_OF(ui);
        const int tj  = TJ_OF(ui);
        if (row != currow) {                  // crossed into row 63-p
            FLUSH_RS(currow);
            LOAD_A(row);
            currow = row;
        }
        if (ui + 1 < u1) STAGE_B(TJ_OF(ui + 1), buf ^ 1);

        float4v acc[4][4];
#pragma unroll
        for (int mi = 0; mi < 4; ++mi)
#pragma unroll
            for (int ni = 0; ni < 4; ++ni)
                acc[mi][ni] = (float4v){0.f, 0.f, 0.f, 0.f};

        const unsigned char* lb = &lsB[buf][0];
        __builtin_amdgcn_s_setprio(1);
#ifdef HAVE_MX
#pragma unroll
        for (int ks = 0; ks < 2; ++ks) {
            const int kp0 = ks * 8 + quad * 2;
            int8v bfv[4];
#pragma unroll
            for (int ni = 0; ni < 4; ++ni) {
                const unsigned char* pB = lb +
                    ((size_t)kp0 * 128 + wn * 64 + ni * 16 + l15) * 16;
                int4v lo = *(const int4v*)pB;
                int4v hi = *(const int4v*)(pB + 2048);   // kp0+1 slot
                bfv[ni] = __builtin_shufflevector(lo, hi, 0,1,2,3,4,5,6,7);
            }
#pragma unroll
            for (int mi = 0; mi < 4; ++mi)
#pragma unroll
                for (int ni = 0; ni < 4; ++ni)
                    acc[mi][ni] = __builtin_amdgcn_mfma_scale_f32_16x16x128_f8f6f4(
                        afr[mi][ks], bfv[ni], acc[mi][ni],
                        0, 0,                     // cbsz=E4M3, blgp=E4M3
                        0, 0x7F7F7F7F,            // scale A = 1.0
                        0, 0x7F7F7F7F);           // scale B = 1.0
        }
#else
#pragma unroll
        for (int kc = 0; kc < 8; ++kc) {
            const int kseg = kc * 4 + quad;
            const int kp   = kseg >> 1;
            const int hf   = kseg & 1;
            long bfv[4];
#pragma unroll
            for (int ni = 0; ni < 4; ++ni)
                bfv[ni] = *(const long*)(lb +
                    ((size_t)kp * 128 + wn * 64 + ni * 16 + l15) * 16 + hf * 8);
#pragma unroll
            for (int mi = 0; mi < 4; ++mi)
#pragma unroll
                for (int ni = 0; ni < 4; ++ni)
                    acc[mi][ni] = __builtin_amdgcn_mfma_f32_16x16x32_fp8_fp8(
                        afr[mi][kc], bfv[ni], acc[mi][ni], 0, 0, 0);
        }
#endif
        __builtin_amdgcn_s_setprio(0);

        // ---- cross tile: extract (q,q+4096) dots (raw acc, BEFORE exp)
        if (tj == row + 32) {
#pragma unroll
            for (int mi = 0; mi < 4; ++mi)
#pragma unroll
                for (int ni = 0; ni < 4; ++ni)
#pragma unroll
                    for (int reg = 0; reg < 4; ++reg) {
                        const int r = wm * 64 + mi * 16 + quad * 4 + reg;
                        const int c = wn * 64 + ni * 16 + l15;
                        if (r == c) dsum += acc[mi][ni][reg];
                    }
        }

        // ---- exp2 in place (acc already = 2*log2e*dot via zn8 scaling)
#pragma unroll
        for (int mi = 0; mi < 4; ++mi)
#pragma unroll
            for (int ni = 0; ni < 4; ++ni)
#pragma unroll
                for (int reg = 0; reg < 4; ++reg)
                    acc[mi][ni][reg] = EXP2F(acc[mi][ni][reg]);

        // ---- row sums accumulate in regs
#pragma unroll
        for (int mi = 0; mi < 4; ++mi)
#pragma unroll
            for (int reg = 0; reg < 4; ++reg)
                rs[mi][reg] += acc[mi][0][reg] + acc[mi][1][reg]
                             + acc[mi][2][reg] + acc[mi][3][reg];

        // ---- col sums (symmetry): per-wave 64-row partial -> own plane
        if (tj > row) {
            float* Cd = Cc + ((size_t)batch * 128 + row * 2 + wm) * 8192
                        + tj * 128 + wn * 64;
#pragma unroll
            for (int ni = 0; ni < 4; ++ni) {
                float s = 0.f;
#pragma unroll
                for (int mi = 0; mi < 4; ++mi)
#pragma unroll
                    for (int reg = 0; reg < 4; ++reg)
                        s += acc[mi][ni][reg];
                s += __shfl_xor(s, 16); s += __shfl_xor(s, 32);
                if (quad == 0)
                    Cd[ni * 16 + l15] = s;
            }
        }
        __syncthreads();                      // single per-tile barrier
    }

    FLUSH_RS(currow);

    // dv = 2*log2e * sum(d);  need -0.5*sum(d) -> factor -0.25*ln2
    {
        float dv = dsum;
        dv += __shfl_xor(dv, 1);  dv += __shfl_xor(dv, 2);
        dv += __shfl_xor(dv, 4);  dv += __shfl_xor(dv, 8);
        dv += __shfl_xor(dv, 16); dv += __shfl_xor(dv, 32);
        if (lane == 0 && dv != 0.f)
            atomicAdd(out, -0.17328680f * dv);
    }
#undef STAGE_B
#undef LOAD_A
#undef FLUSH_RS
#undef TJ_OF
#undef ROW_OF
}

// ---------------------------------------------------------------------------
// final: out += 0.125 * sum_{b,q} log(S[b][q] + sum_{r<2*(q>>7)} Cc[b][r][q] - e^2)
// grid 128 x 256 (one thread per (b,q)).  Only valid (written) planes read.
// ---------------------------------------------------------------------------
__global__ __launch_bounds__(256) void final_log_kernel(
    const float* __restrict__ S, const float* __restrict__ Cc,
    float* __restrict__ out)
{
    __shared__ float red[4];
    const int tid  = threadIdx.x;
    const int w    = tid >> 6;
    const int lane = tid & 63;
    const float E2 = 7.3890560989306495f;

    const int i = blockIdx.x * 256 + tid;     // 0..32767
    const int b = i >> 13;
    const int q = i & 8191;
    float s = S[i];
    const float* Cp = Cc + (size_t)b * 128 * 8192 + q;
    const int np = (q >> 7) * 2;              // planes 0..np-1 are written
    for (int r = 0; r < np; ++r)
        s += Cp[(size_t)r * 8192];
    float acc = logf(s - E2);

    acc += __shfl_xor(acc, 1);  acc += __shfl_xor(acc, 2);
    acc += __shfl_xor(acc, 4);  acc += __shfl_xor(acc, 8);
    acc += __shfl_xor(acc, 16); acc += __shfl_xor(acc, 32);
    if (lane == 0) red[w] = acc;
    __syncthreads();
    if (tid == 0)
        atomicAdd(out, 0.125f * (red[0] + red[1] + red[2] + red[3]));
}

// ---------------------------------------------------------------------------
// Workspace (bytes), total ~25.6 MB:
//   [0,       131072)  S (4*8192 fp32)
//   [131072,  262144)  W1bf
//   [262144,  393216)  W2bf
//   [393216,  8781824) zn8 (fp8, 8.39MB)
//   [8781824, 25559040) Cc (col-sum planes, 4*128*8192 fp32 = 16.78MB;
//                      no memset: final reads only written planes)
// ---------------------------------------------------------------------------
extern "C" void kernel_launch(void* const* d_in, const int* in_sizes, int n_in,
                              void* d_out, int out_size, void* d_ws, size_t ws_size,
                              hipStream_t stream)
{
    const float* X1 = (const float*)d_in[0];
    const float* X2 = (const float*)d_in[1];
    const float* W1 = (const float*)d_in[2];
    const float* b1 = (const float*)d_in[3];
    const float* W2 = (const float*)d_in[4];
    const float* b2 = (const float*)d_in[5];

    char* ws = (char*)d_ws;
    float* S    = (float*)(ws + 0);
    short* W1bf = (short*)(ws + 131072);
    short* W2bf = (short*)(ws + 262144);
    unsigned char* zn8 = (unsigned char*)(ws + 393216);
    float* Cc   = (float*)(ws + 8781824);

    convW_zero_kernel<<<128, 256, 0, stream>>>(W1, W2, W1bf, W2bf,
                                               S, (float*)d_out);
    fusedproj_kernel<<<512, 256, 0, stream>>>(X1, X2, W1bf, b1, W2bf, b2, zn8);
    gram_fp8_sym_kernel<<<512, 256, 0, stream>>>(zn8, S, Cc, (float*)d_out);
    final_log_kernel<<<128, 256, 0, stream>>>(S, Cc, (float*)d_out);
}